// Round 8
// baseline (1664.521 us; speedup 1.0000x reference)
//
#include <hip/hip_runtime.h>
#include <hip/hip_bf16.h>
#include <hip/hip_fp16.h>

// T=5, B=4, M=4096, N=16384, C=128, G=1024, H=4, K=16. fp32 in/out.

typedef __bf16 v8bf __attribute__((ext_vector_type(8)));
typedef float  v4f  __attribute__((ext_vector_type(4)));

__device__ __forceinline__ float lrelu(float x) { return fmaxf(x, 0.2f * x); }

__device__ __forceinline__ unsigned short f2bf(float x) {
  __hip_bfloat16 h = __float2bfloat16(x);
  return __builtin_bit_cast(unsigned short, h);
}
__device__ __forceinline__ float bf2f(unsigned short u) {
  unsigned int t = ((unsigned int)u) << 16;
  return __builtin_bit_cast(float, t);
}

// order-preserving float<->uint key (sign-flip trick)
__device__ __forceinline__ unsigned fkey(float v) {
  unsigned b = __builtin_bit_cast(unsigned, v);
  return b ^ (((unsigned)((int)b >> 31)) | 0x80000000u);
}
__device__ __forceinline__ float finv(unsigned k) {
  unsigned m = (unsigned)((int)k >> 31);           // all-1s iff encoded-positive
  unsigned b = k ^ ((~m) | 0x80000000u);
  return __builtin_bit_cast(float, b);
}

#define GLOAD_LDS16(gp, lp)                                                   \
  __builtin_amdgcn_global_load_lds(                                           \
      (const __attribute__((address_space(1))) void*)(gp),                    \
      (__attribute__((address_space(3))) void*)(lp), 16, 0, 0)

// raw barrier (no vmcnt drain) + IR-level memory fence
#define RBAR() do { __builtin_amdgcn_s_barrier(); asm volatile("" ::: "memory"); } while (0)
// intra-wave LDS drain (no barrier): orders LDS atomics/writes vs later reads
#define LWAIT() do { asm volatile("s_waitcnt lgkmcnt(0)" ::: "memory");        \
                     __builtin_amdgcn_sched_barrier(0); } while (0)

// ---------------------------------------------------------------------------
// Unified NT bf16 MFMA GEMM (MLP + projections) — unchanged.
// ---------------------------------------------------------------------------
template<int EP>
__global__ __launch_bounds__(256, 2)
void nt_mfma(const unsigned short* __restrict__ A, const unsigned short* __restrict__ B,
             const float* __restrict__ aux, void* __restrict__ outv, int K, int ldc)
{
  __shared__ __align__(16) unsigned short smem[3 * 8192];  // 3 x (A 4096 + B 4096)
  const int tid = threadIdx.x;
  const int l = tid & 63;
  const int w = tid >> 6;
  const int wm = w & 1, wn = w >> 1;
  const int m0 = blockIdx.y << 7, n0 = blockIdx.x << 7;
  const int fr = l & 15, quad = l >> 4;
  const int kt = K >> 5;
  const int xq4 = quad ^ ((fr >> 1) & 3);           // read-side swizzle slot

  const int r0 = tid >> 2;
  const int sw = (tid & 3) ^ ((tid >> 3) & 3);      // source-side swizzle slot
  const unsigned short* Aa = A + (size_t)(m0 + r0) * K + sw * 8;
  const unsigned short* Ab = Aa + (size_t)64 * K;
  const unsigned short* Ba = B + (size_t)(n0 + r0) * K + sw * 8;
  const unsigned short* Bb = Ba + (size_t)64 * K;

  auto stage = [&](int bi, int ks) {
    unsigned short* As = smem + bi * 8192;
    unsigned short* Bs = As + 4096;
    GLOAD_LDS16(Aa + ks * 32, As + tid * 8);
    GLOAD_LDS16(Ab + ks * 32, As + (tid + 256) * 8);
    GLOAD_LDS16(Ba + ks * 32, Bs + tid * 8);
    GLOAD_LDS16(Bb + ks * 32, Bs + (tid + 256) * 8);
  };

  v4f acc[4][4];
#pragma unroll
  for (int i = 0; i < 4; ++i)
#pragma unroll
    for (int j = 0; j < 4; ++j) acc[i][j] = (v4f){0.f, 0.f, 0.f, 0.f};

  stage(0, 0);
  if (kt > 1) stage(1, 1);
  int cur = 0, pend = (kt > 1) ? 2 : 1, sn = 2;

  for (int ks = 0; ks < kt; ++ks) {
    if (pend == 2) asm volatile("s_waitcnt vmcnt(4)" ::: "memory");
    else           asm volatile("s_waitcnt vmcnt(0)" ::: "memory");
    RBAR();
    int nb = cur + 2; if (nb >= 3) nb -= 3;
    if (sn < kt) { stage(nb, sn); ++sn; } else { --pend; }
    const unsigned short* As = smem + cur * 8192;
    const unsigned short* Bs = As + 4096;
    v8bf af[4], bfr[4];
#pragma unroll
    for (int i = 0; i < 4; ++i)
      af[i] = *(const v8bf*)(As + (wm * 64 + i * 16 + fr) * 32 + xq4 * 8);
#pragma unroll
    for (int j = 0; j < 4; ++j)
      bfr[j] = *(const v8bf*)(Bs + (wn * 64 + j * 16 + fr) * 32 + xq4 * 8);
#pragma unroll
    for (int i = 0; i < 4; ++i)
#pragma unroll
      for (int j = 0; j < 4; ++j)
        acc[i][j] = __builtin_amdgcn_mfma_f32_16x16x32_bf16(af[i], bfr[j], acc[i][j], 0, 0, 0);
    __builtin_amdgcn_sched_barrier(0);
    if (++cur == 3) cur = 0;
  }

  if (EP == 1) {
    unsigned short* O = (unsigned short*)outv;
#pragma unroll
    for (int j = 0; j < 4; ++j) {
      int col = n0 + wn * 64 + j * 16 + fr;
      float bias = aux[col];
#pragma unroll
      for (int i = 0; i < 4; ++i) {
        int row = m0 + wm * 64 + i * 16 + quad * 4;
#pragma unroll
        for (int r = 0; r < 4; ++r)
          O[(size_t)(row + r) * ldc + col] = f2bf(lrelu(acc[i][j][r] + bias));
      }
    }
  } else if (EP == 2) {
    __syncthreads();
    float* red = (float*)smem;
#pragma unroll
    for (int j = 0; j < 4; ++j) {
      int lcol = wn * 64 + j * 16 + fr;
      float bias = aux[n0 + lcol];
      float s = 0.f;
#pragma unroll
      for (int i = 0; i < 4; ++i)
#pragma unroll
        for (int r = 0; r < 4; ++r) s += lrelu(acc[i][j][r] + bias);
      s += __shfl_xor(s, 16);
      s += __shfl_xor(s, 32);
      if (quad == 0) red[w * 128 + lcol] = s;
    }
    __syncthreads();
    if (tid < 128) {
      float s = (tid < 64) ? red[0 * 128 + tid] + red[1 * 128 + tid]
                           : red[2 * 128 + tid] + red[3 * 128 + tid];
      atomicAdd((float*)outv + ((m0 >> 12) << 10) + n0 + tid, s * (1.0f / 4096.0f));
    }
  } else {  // EP == 3: half store
    __half* O = (__half*)outv;
#pragma unroll
    for (int j = 0; j < 4; ++j) {
      int col = n0 + wn * 64 + j * 16 + fr;
#pragma unroll
      for (int i = 0; i < 4; ++i) {
        int row = m0 + wm * 64 + i * 16 + quad * 4;
#pragma unroll
        for (int r = 0; r < 4; ++r)
          O[(size_t)(row + r) * ldc + col] = __float2half(acc[i][j][r]);
      }
    }
  }
}

// ---------------------------------------------------------------------------
// knn_coarse v9 = v8 machinery + occupancy fill + VALU-lean scan:
//  - COLUMN SPLIT: each block covers 64 rows x 2048 cols (half h); grid 2048,
//    __launch_bounds__(256,8) -> 8 blocks/CU (156 KB LDS, 64-VGPR budget).
//    Each half emits an exact top-20 (packed keys) of its cols; knn_merge
//    merges the two sorted lists -> identical set to single-pass top-20.
//  - ROW-MAX GATE: per r, 7-fmax tree + one >= compare (matches scan's >=;
//    seed tau is an actual value, > would drop equality hits) gates the
//    32-compare scan -> common-case ~64 VALU/tile instead of ~160.
//  - ZERO-PUSH FAST EXIT: when no lane pushed this round, skip the merge
//    phase (2 LWAIT + shfl) entirely.
// ---------------------------------------------------------------------------
#define TOPN 20
#define FB   10   // push-buffer capacity per row per pass
#define PSTR 11   // push row stride (odd)

__global__ __launch_bounds__(256, 8)
void knn_coarse(const unsigned short* __restrict__ seqbf,
                const float* __restrict__ xsq, unsigned* __restrict__ ckeys)
{
  __shared__ __align__(16) unsigned short bsm[8192];  // 16 KB: B half-tile (2 k-chunks)
  __shared__ unsigned pushK[64 * PSTR];
  __shared__ int      cntW[64];

  const int tid = threadIdx.x;
  const int l = tid & 63;
  const int w = tid >> 6;
  const int blk = blockIdx.x;
  const int pair = ((blk & 7) << 1) | ((blk >> 3) & 1);  // XCD-aligned (f,b)
  const int h = (blk >> 4) & 1;                          // column half
  const int rb = blk >> 5;                               // 0..63
  const int f = pair >> 2, b = pair & 3;
  const int m0 = rb << 6;                                // 64-row block
  const int fr = l & 15, quad = l >> 4;
  const int xq4 = quad ^ ((fr >> 1) & 3);

  const unsigned short* ybase = seqbf + ((size_t)65536 + b * 4096) * 128;
  const unsigned short* xbase = seqbf + ((size_t)(f * 16384 + b * 4096)) * 128;
  const float* xq = xsq + f * 16384 + b * 4096;

  const int r0 = tid >> 2;
  const int sw = (tid & 3) ^ ((tid >> 3) & 3);

  // A fragments straight from global: warp w owns rows [w*16, w*16+16)
  v8bf afr[4];
#pragma unroll
  for (int ksp = 0; ksp < 4; ++ksp)
    afr[ksp] = *(const v8bf*)(ybase + (size_t)(m0 + w * 16 + fr) * 128 + ksp * 32 + quad * 8);

  // register top-list (packed keys, descending); valid on owner lanes l<16
  unsigned tk[TOPN];
#pragma unroll
  for (int k = 0; k < TOPN; ++k) tk[k] = 0u;
  float tauReg = -3.0e38f;
  if (l < 16) cntW[w * 16 + l] = 0;
  float tc[4];
#pragma unroll
  for (int r = 0; r < 4; ++r) tc[r] = -3.0e38f;
  LWAIT();

  for (int ct = 0; ct < 16; ++ct) {
    const int n0 = (h << 11) + (ct << 7);
    const unsigned short* Bt = xbase + (size_t)(n0 + r0) * 128 + sw * 8;

    // ---- half 0: k-chunks 0,1 ----
    RBAR();  // fence vs all warps' prev-tile half-1 ds_reads
    GLOAD_LDS16(Bt, bsm + tid * 8);
    GLOAD_LDS16(Bt + 64 * 128, bsm + (tid + 256) * 8);
    GLOAD_LDS16(Bt + 32, bsm + 4096 + tid * 8);
    GLOAD_LDS16(Bt + 64 * 128 + 32, bsm + 4096 + (tid + 256) * 8);
    float xsv[8];
#pragma unroll
    for (int j = 0; j < 8; ++j) xsv[j] = xq[n0 + j * 16 + fr];
    asm volatile("s_waitcnt vmcnt(0)" ::: "memory");
    RBAR();

    v4f acc[8];
#pragma unroll
    for (int j = 0; j < 8; ++j) acc[j] = (v4f){0.f, 0.f, 0.f, 0.f};

#pragma unroll
    for (int ksp = 0; ksp < 2; ++ksp) {
      v8bf bfr[8];
#pragma unroll
      for (int j = 0; j < 8; ++j)
        bfr[j] = *(const v8bf*)(bsm + ksp * 4096 + (j * 16 + fr) * 32 + xq4 * 8);
#pragma unroll
      for (int j = 0; j < 8; ++j)
        acc[j] = __builtin_amdgcn_mfma_f32_16x16x32_bf16(afr[ksp], bfr[j], acc[j], 0, 0, 0);
    }
    LWAIT();
    RBAR();

    // ---- half 1: k-chunks 2,3 ----
    GLOAD_LDS16(Bt + 2 * 32, bsm + tid * 8);
    GLOAD_LDS16(Bt + 64 * 128 + 2 * 32, bsm + (tid + 256) * 8);
    GLOAD_LDS16(Bt + 3 * 32, bsm + 4096 + tid * 8);
    GLOAD_LDS16(Bt + 64 * 128 + 3 * 32, bsm + 4096 + (tid + 256) * 8);
    asm volatile("s_waitcnt vmcnt(0)" ::: "memory");
    RBAR();

#pragma unroll
    for (int ksp = 0; ksp < 2; ++ksp) {
      v8bf bfr[8];
#pragma unroll
      for (int j = 0; j < 8; ++j)
        bfr[j] = *(const v8bf*)(bsm + ksp * 4096 + (j * 16 + fr) * 32 + xq4 * 8);
#pragma unroll
      for (int j = 0; j < 8; ++j)
        acc[j] = __builtin_amdgcn_mfma_f32_16x16x32_bf16(afr[2 + ksp], bfr[j], acc[j], 0, 0, 0);
    }

    // fold v = 2*acc - xs in place
#pragma unroll
    for (int j = 0; j < 8; ++j)
#pragma unroll
      for (int r = 0; r < 4; ++r)
        acc[j][r] = 2.f * acc[j][r] - xsv[j];

    if (ct == 0) {
      // tau seed: per row, min over 16 fr-lanes of lane-2nd-max (valid lower
      // bound: >=32 values >= tau0 per row -> fills TOPN=20)
#pragma unroll
      for (int r = 0; r < 4; ++r) {
        float t1 = fmaxf(acc[0][r], acc[1][r]);
        float t2 = fminf(acc[0][r], acc[1][r]);
#pragma unroll
        for (int j = 2; j < 8; ++j) {
          float v = acc[j][r];
          float hi = fmaxf(t1, v);
          t2 = fmaxf(t2, fminf(t1, v));
          t1 = hi;
        }
#pragma unroll
        for (int off = 1; off <= 8; off <<= 1)
          t2 = fminf(t2, __shfl_xor(t2, off));
        tc[r] = t2;
        float tq = __shfl(t2, (l >> 2) << 4);   // value from target row's quad
        if (l < 16 && (l & 3) == r) tauReg = tq;
      }
    }

    // ---- warp-private exact top-20: row-max gate + push + reg-merge ----
    unsigned int pushed = 0u;
    for (;;) {
      bool didPush = false;
      // gate: per r, max over j then one compare (>= matches scan predicate)
      int hit = 0;
#pragma unroll
      for (int r = 0; r < 4; ++r) {
        float m = acc[0][r];
#pragma unroll
        for (int j = 1; j < 8; ++j) m = fmaxf(m, acc[j][r]);
        if (m >= tc[r]) hit |= 1 << r;
      }
      if (__any(hit != 0)) {
#pragma unroll
        for (int r = 0; r < 4; ++r) {
          if (__any(hit & (1 << r))) {
            const float tau = tc[r];
            int mca = 0;
#pragma unroll
            for (int j = 0; j < 8; ++j) {
              const int bit = j * 4 + r;
              if (acc[j][r] >= tau && !((pushed >> bit) & 1u)) mca |= (1 << j);
            }
            if (__any(mca != 0)) {
              const int lrow = w * 16 + quad * 4 + r;
#pragma unroll
              for (int j = 0; j < 8; ++j)
                if ((mca >> j) & 1) {
                  int pos = atomicAdd(&cntW[lrow], 1);
                  if (pos < FB) {
                    pushK[lrow * PSTR + pos] =
                        (fkey(acc[j][r]) & 0xFFFFF000u) | (unsigned)(n0 + j * 16 + fr);
                    pushed |= (1u << (j * 4 + r));
                    didPush = true;
                  }
                }
            }
          }
        }
      }
      if (!__any(didPush)) break;   // nothing pushed anywhere -> done, skip merge
      LWAIT();
      bool ov = false;
      if (l < 16) {
        const int grow = w * 16 + l;
        int c = cntW[grow];
        int cc = c < FB ? c : FB;
        for (int q = 0; q < cc; ++q) {
          unsigned k = pushK[grow * PSTR + q];
          if (k > tk[TOPN - 1]) {
            // static-unrolled descending sorted insert (registers only)
#pragma unroll
            for (int i = TOPN - 1; i >= 1; --i)
              tk[i] = (k > tk[i - 1]) ? tk[i - 1] : (k > tk[i] ? k : tk[i]);
            tk[0] = (k > tk[0]) ? k : tk[0];
          }
        }
        if (tk[TOPN - 1] != 0u)
          tauReg = fmaxf(tauReg, finv(tk[TOPN - 1] & 0xFFFFF000u));
        ov = c > FB;
        cntW[grow] = 0;
      }
      LWAIT();
#pragma unroll
      for (int r = 0; r < 4; ++r)
        tc[r] = __shfl(tauReg, quad * 4 + r);   // owner lane of row quad*4+r
      if (!__any(ov)) break;
    }
  }

  if (l < 16) {
    const int grow = w * 16 + l;
    unsigned* outp = ckeys + ((size_t)(f * 16384 + b * 4096 + m0 + grow)) * 40 + h * 20;
#pragma unroll
    for (int k = 0; k < TOPN; ++k) outp[k] = tk[k];
  }
}

// ---------------------------------------------------------------------------
// knn_merge: merge the two per-half descending top-20 key lists into one
// top-20 index list per row. Coalesced block-load into LDS; per-thread
// 2-pointer merge (runtime LDS indexing is fine; registers hold heads only).
// Union top-20 == single-pass top-20 (same keys) -> downstream bit-identical.
// ---------------------------------------------------------------------------
__global__ __launch_bounds__(256)
void knn_merge(const unsigned* __restrict__ ckeys, int* __restrict__ cand20)
{
  __shared__ unsigned lbuf[256 * 40];
  const int tid = threadIdx.x;
  const size_t base = (size_t)blockIdx.x * 10240;   // 256 rows x 40 keys
#pragma unroll
  for (int i = 0; i < 40; ++i)
    lbuf[tid + i * 256] = ckeys[base + tid + i * 256];
  LWAIT();
  __syncthreads();
  const unsigned* A = lbuf + tid * 40;        // [0..20) half 0, [20..40) half 1
  int ia = 0, ib = 20;
  unsigned ka = A[0], kb = A[20];
  int* outp = cand20 + ((size_t)blockIdx.x * 256 + tid) * 20;
#pragma unroll
  for (int k = 0; k < 20; ++k) {
    bool ta = ka >= kb;
    outp[k] = (int)((ta ? ka : kb) & 0xFFFu);
    if (ta) { ++ia; ka = (ia < 20) ? A[ia] : 0u; }
    else    { ++ib; kb = (ib < 40) ? A[ib] : 0u; }
  }
}

// ---------------------------------------------------------------------------
// knn_rescore v4 (unchanged): exact fp32 rescoring of 20 candidates -> top-16.
// ---------------------------------------------------------------------------
__global__ __launch_bounds__(256)
void knn_rescore(const float* __restrict__ seq, const float* __restrict__ xsq,
                 const int* __restrict__ cand, int* __restrict__ nbrOut)
{
  __shared__ float sc[4][20];
  const int tid = threadIdx.x;
  const int l = tid & 63;
  const int wq = tid >> 6;                    // query within block
  const int blk = blockIdx.x;
  const int pair = ((blk & 7) << 1) | ((blk >> 3) & 1);
  const int qb = blk >> 4;                    // 0..1023
  const int f = pair >> 2, b = pair & 3;
  const int qloc = qb * 4 + wq;               // 0..4095
  const int gq = pair * 4096 + qloc;          // = f*16384 + b*4096 + qloc

  const int c8 = l & 7;                       // candidate slot in round
  const int h  = l >> 3;                      // chunk 0..7
  const float* yrow = seq + ((size_t)65536 + b * 4096 + qloc) * 128 + h * 16;
  float4 y0 = *(const float4*)(yrow);
  float4 y1 = *(const float4*)(yrow + 4);
  float4 y2 = *(const float4*)(yrow + 8);
  float4 y3 = *(const float4*)(yrow + 12);
  const float* xslice = seq + (size_t)(f * 16384 + (b << 12)) * 128;
  const float* xsqs = xsq + f * 16384 + (b << 12);
  const int* cq = cand + (size_t)gq * 20;

#pragma unroll
  for (int rd = 0; rd < 3; ++rd) {
    int cr = rd * 8 + c8;
    int crc = cr < 20 ? cr : 0;
    int cj = cq[crc];
    const float* xr = xslice + (size_t)cj * 128 + h * 16;
    float4 x0 = *(const float4*)(xr);
    float4 x1 = *(const float4*)(xr + 4);
    float4 x2 = *(const float4*)(xr + 8);
    float4 x3 = *(const float4*)(xr + 12);
    float p = y0.x * x0.x + y0.y * x0.y + y0.z * x0.z + y0.w * x0.w
            + y1.x * x1.x + y1.y * x1.y + y1.z * x1.z + y1.w * x1.w
            + y2.x * x2.x + y2.y * x2.y + y2.z * x2.z + y2.w * x2.w
            + y3.x * x3.x + y3.y * x3.y + y3.z * x3.z + y3.w * x3.w;
    p += __shfl_xor(p, 8);
    p += __shfl_xor(p, 16);
    p += __shfl_xor(p, 32);
    if (h == 0 && cr < 20) sc[wq][cr] = 2.f * p - xsqs[cj];
  }
  LWAIT();   // sc written/read by the same wave only
  if (l < 20) {
    float myv = sc[wq][l];
    int rank = 0;
#pragma unroll
    for (int j = 0; j < 20; ++j) {
      float vj = sc[wq][j];
      rank += (vj > myv || (vj == myv && j < l)) ? 1 : 0;
    }
    if (rank < 16)
      nbrOut[(size_t)gq * 16 + rank] = (b << 12) + cq[l];
  }
}

// ---------------------------------------------------------------------------
// convert_inputs (unchanged)
// ---------------------------------------------------------------------------
__global__ __launch_bounds__(256)
void convert_inputs(const float* __restrict__ seq, unsigned short* __restrict__ seqbf,
                    unsigned short* __restrict__ ylay, unsigned short* __restrict__ xlay,
                    float* __restrict__ xsq)
{
  const int tid = threadIdx.x;
  const int row = blockIdx.x * 8 + (tid >> 5);
  const int c4 = tid & 31;
  float4 v = *(const float4*)(seq + (size_t)row * 128 + c4 * 4);
  ushort4 hi, lo;
  hi.x = f2bf(v.x); lo.x = f2bf(v.x - bf2f(hi.x));
  hi.y = f2bf(v.y); lo.y = f2bf(v.y - bf2f(hi.y));
  hi.z = f2bf(v.z); lo.z = f2bf(v.z - bf2f(hi.z));
  hi.w = f2bf(v.w); lo.w = f2bf(v.w - bf2f(hi.w));
  *(ushort4*)(seqbf + (size_t)row * 128 + c4 * 4) = hi;
  float ss = v.x * v.x + v.y * v.y + v.z * v.z + v.w * v.w;
#pragma unroll
  for (int off = 16; off; off >>= 1) ss += __shfl_xor(ss, off);
  if (row < 65536) {
    unsigned short* p = xlay + (size_t)row * 384 + c4 * 4;
    *(ushort4*)(p) = hi; *(ushort4*)(p + 128) = lo; *(ushort4*)(p + 256) = hi;
    if (c4 == 0) xsq[row] = ss;
  } else {
    unsigned short* p = ylay + (size_t)(row - 65536) * 384 + c4 * 4;
    *(ushort4*)(p) = hi; *(ushort4*)(p + 128) = hi; *(ushort4*)(p + 256) = lo;
  }
}

// ---------------------------------------------------------------------------
// convert_weights (unchanged)
// ---------------------------------------------------------------------------
__global__ __launch_bounds__(256)
void convert_weights(const float* __restrict__ W1, const float* __restrict__ W2,
                     const float* __restrict__ Wl, const float* __restrict__ Wr,
                     const float* __restrict__ aw,
                     unsigned short* __restrict__ W1t, unsigned short* __restrict__ W2t,
                     unsigned short* __restrict__ Wlv, unsigned short* __restrict__ Wrv,
                     __half* __restrict__ awh)
{
  int idx = blockIdx.x * 256 + threadIdx.x;
  if (idx < 16384) {
    int n = idx >> 7, k = idx & 127;
    W1t[idx] = f2bf(W1[k * 128 + n]);
  } else if (idx < 147456) {
    int i = idx - 16384; int n = i >> 7, k = i & 127;
    W2t[i] = f2bf(W2[k * 1024 + n]);
  } else if (idx < 344064) {
    int i = idx - 147456; int n = i / 384, k = i % 384;
    int s = k >> 7, kk = k & 127;
    float wv = Wl[kk * 512 + n];
    unsigned short h = f2bf(wv);
    Wlv[i] = (s == 1) ? f2bf(wv - bf2f(h)) : h;
  } else if (idx < 540672) {
    int i = idx - 344064; int n = i / 384, k = i % 384;
    int s = k >> 7, kk = k & 127;
    float wv = Wr[kk * 512 + n];
    unsigned short h = f2bf(wv);
    Wrv[i] = (s == 2) ? f2bf(wv - bf2f(h)) : h;
  } else if (idx < 541184) {
    int i = idx - 540672;
    awh[i] = __float2half(aw[i]);
  }
}

// ---------------------------------------------------------------------------
// Temporal attention weights (unchanged)
// ---------------------------------------------------------------------------
__global__ __launch_bounds__(1024)
void temporal_attn(const float* __restrict__ gfea, float* __restrict__ attnw)
{
  const int tid = threadIdx.x;
  const int w = tid >> 6, l = tid & 63;
  const int b = w >> 2, i = w & 3;
  const float* q  = gfea + (16 + b) * 1024;
  const float* kv = gfea + (i * 4 + b) * 1024;
  float p = 0.f;
  for (int g = l; g < 1024; g += 64) p += q[g] * kv[g];
#pragma unroll
  for (int off = 32; off; off >>= 1) p += __shfl_xor(p, off);
  __shared__ float sc[16];
  if (l == 0) sc[w] = p * 0.03125f;
  __syncthreads();
  if (tid < 4) {
    float v0 = sc[tid * 4 + 0], v1 = sc[tid * 4 + 1];
    float v2 = sc[tid * 4 + 2], v3 = sc[tid * 4 + 3];
    float mm = fmaxf(fmaxf(v0, v1), fmaxf(v2, v3));
    v0 = __expf(v0 - mm); v1 = __expf(v1 - mm);
    v2 = __expf(v2 - mm); v3 = __expf(v3 - mm);
    float inv = 1.f / (v0 + v1 + v2 + v3);
    attnw[tid * 4 + 0] = v0 * inv;
    attnw[tid * 4 + 1] = v1 * inv;
    attnw[tid * 4 + 2] = v2 * inv;
    attnw[tid * 4 + 3] = v3 * inv;
  }
}

// ---------------------------------------------------------------------------
// gat6 (chunked single-fetch) + XCD-aware swizzle (unchanged)
// ---------------------------------------------------------------------------
__global__ __launch_bounds__(256)
void gat6(const __half* __restrict__ xlh, const __half* __restrict__ xrh,
          const int* __restrict__ nbr, const __half* __restrict__ awh,
          const float* __restrict__ attnw, float* __restrict__ wgt4)
{
  const int tid = threadIdx.x;
  const int l = tid & 63;
  const int blk = blockIdx.x;
  const int r8 = blk & 7;
  const int b = r8 >> 1;                      // XCD pair -> batch
  const int g = ((blk >> 3) << 1) | (r8 & 1); // [0, 4096)
  const int f = g >> 10;
  const int n4 = g & 1023;
  const int qid = f * 16384 + b * 4096 + n4 * 4 + (tid >> 6);
  const int h = l >> 4, cp = l & 15;
  const float fw = attnw[b * 4 + f] * 0.25f;

  const int jl = nbr[qid * 16 + (l & 15)];
  const __half* xbase = xlh + h * 128 + cp * 8;

  const __half2* xrp = (const __half2*)(xrh + (size_t)qid * 512 + h * 128 + cp * 8);
  float2 xr0 = __half22float2(xrp[0]), xr1 = __half22float2(xrp[1]);
  float2 xr2 = __half22float2(xrp[2]), xr3 = __half22float2(xrp[3]);
  const __half2* awp = (const __half2*)(awh + h * 128 + cp * 8);
  float2 aw0 = __half22float2(awp[0]), aw1 = __half22float2(awp[1]);
  float2 aw2 = __half22float2(awp[2]), aw3 = __half22float2(awp[3]);

  float m = -3.0e38f, s = 0.f;
  float o[8];
#pragma unroll
  for (int c = 0; c < 8; ++c) o[c] = 0.f;

  for (int ch = 0; ch < 2; ++ch) {
    float4 xv[8];
#pragma unroll
    for (int k = 0; k < 8; ++k) {
      int j = __shfl(jl, ch * 8 + k);
      xv[k] = *(const float4*)(xbase + (size_t)j * 512);
    }
    float e[8];
#pragma unroll
    for (int k = 0; k < 8; ++k) {
      const __half2* hp = (const __half2*)&xv[k];
      float2 x0 = __half22float2(hp[0]), x1 = __half22float2(hp[1]);
      float2 x2 = __half22float2(hp[2]), x3 = __half22float2(hp[3]);
      float p = 0.f;
      p += lrelu(x0.x + xr0.x) * aw0.x + lrelu(x0.y + xr0.y) * aw0.y;
      p += lrelu(x1.x + xr1.x) * aw1.x + lrelu(x1.y + xr1.y) * aw1.y;
      p += lrelu(x2.x + xr2.x) * aw2.x + lrelu(x2.y + xr2.y) * aw2.y;
      p += lrelu(x3.x + xr3.x) * aw3.x + lrelu(x3.y + xr3.y) * aw3.y;
      p += __shfl_xor(p, 1);
      p += __shfl_xor(p, 2);
      p += __shfl_xor(p, 4);
      p += __shfl_xor(p, 8);
      e[k] = p;
    }
    float mc = e[0];
#pragma unroll
    for (int k = 1; k < 8; ++k) mc = fmaxf(mc, e[k]);
    float mn = fmaxf(m, mc);
    float cr = __expf(m - mn);
    s *= cr;
#pragma unroll
    for (int c = 0; c < 8; ++c) o[c] *= cr;
#pragma unroll
    for (int k = 0; k < 8; ++k) {
      float a = __expf(e[k] - mn);
      s += a;
      const __half2* hp = (const __half2*)&xv[k];
      float2 f0 = __half22float2(hp[0]);
      float2 f1 = __half22float2(hp[1]);
      float2 f2 = __half22float2(hp[2]);
      float2 f3 = __half22float2(hp[3]);
      o[0] += a * f0.x; o[1] += a * f0.y;
      o[2] += a * f1.x; o[3] += a * f1.y;
      o[4] += a * f2.x; o[5] += a * f2.y;
      o[6] += a * f3.x; o[7] += a * f3.y;
    }
    m = mn;
  }

  const float sc = fw / s;
#pragma unroll
  for (int c = 0; c < 8; ++c) {
    float t = o[c] * sc;
    t += __shfl_xor(t, 16);
    t += __shfl_xor(t, 32);
    o[c] = t;
  }
  if (l < 16) {
    float* wp = wgt4 + (size_t)qid * 128 + l * 8;
    *(float4*)(wp)     = make_float4(o[0], o[1], o[2], o[3]);
    *(float4*)(wp + 4) = make_float4(o[4], o[5], o[6], o[7]);
  }
}

// ---------------------------------------------------------------------------
// finalize (unchanged)
// ---------------------------------------------------------------------------
__global__ __launch_bounds__(256)
void finalize2(const float* __restrict__ last, const float* __restrict__ wgt4,
               float* __restrict__ out)
{
  int idx = blockIdx.x * 256 + threadIdx.x;
  int n = idx >> 6, q = idx & 63;
  float4 v;
  if (q < 32) {
    v = *(const float4*)(last + (size_t)n * 128 + 4 * q);
  } else {
    int c = (q - 32) * 4;
    v = make_float4(0.f, 0.f, 0.f, 0.f);
#pragma unroll
    for (int f = 0; f < 4; ++f) {
      float4 t = *(const float4*)(wgt4 + ((size_t)f * 16384 + n) * 128 + c);
      v.x += t.x; v.y += t.y; v.z += t.z; v.w += t.w;
    }
  }
  *(float4*)(out + (size_t)n * 256 + 4 * q) = v;
}

extern "C" void kernel_launch(void* const* d_in, const int* in_sizes, int n_in,
                              void* d_out, int out_size, void* d_ws, size_t ws_size,
                              hipStream_t stream)
{
  (void)in_sizes; (void)n_in; (void)out_size; (void)ws_size;
  const float* seq = (const float*)d_in[0];
  const float* W1  = (const float*)d_in[1];
  const float* b1  = (const float*)d_in[2];
  const float* W2  = (const float*)d_in[3];
  const float* b2  = (const float*)d_in[4];
  const float* Wl  = (const float*)d_in[5];
  const float* Wr  = (const float*)d_in[6];
  const float* aw  = (const float*)d_in[7];
  float* out = (float*)d_out;

  // workspace layout (float offsets); ~178 MiB total
  float* ws = (float*)d_ws;
  __half* xrh          = (__half*)ws;                          // 65536x512 half (32 MB region)
  unsigned short* seqbf = (unsigned short*)(ws + 16777216);    // 10,485,760 us
  unsigned short* h1bf  = (unsigned short*)(ws + 22020096);    // 10,485,760 us
  unsigned* ckeys       = (unsigned*)(ws + 22020096);          // alias after mlp2: 65536x40 uint
  int* cand20           = (int*)(ws + 22020096 + 2621440);     // 65536x20 int (after ckeys)
  __half* xlh           = (__half*)(ws + 22020096);            // alias after rescore: 16384x512 half
  unsigned short* ylay  = (unsigned short*)(ws + 27262976);    // 6,291,456 us
  unsigned short* xlay  = (unsigned short*)(ws + 30408704);    // 25,165,824 us
  float* wgt4           = ws + 30408704;                       // alias after xr gemm: 8,388,608 f
  float* gfea           = ws + 42991616;                       // 20,480
  float* attn           = gfea + 20480;                        // 16
  float* xsq            = attn + 16;                           // 65,536
  int*   nbr            = (int*)(xsq + 65536);                 // 1,048,576 ints
  unsigned short* W1t   = (unsigned short*)(nbr + 1048576);    // 16,384 us
  unsigned short* W2t   = W1t + 16384;                         // 131,072 us
  unsigned short* Wlv   = W2t + 131072;                        // 196,608 us
  unsigned short* Wrv   = Wlv + 196608;                        // 196,608 us
  __half* awh           = (__half*)(Wrv + 196608);             // 512 halves

  (void)hipMemsetAsync(gfea, 0, 20480 * sizeof(float), stream);

  // conversions
  convert_inputs<<<10240, 256, 0, stream>>>(seq, seqbf, ylay, xlay, xsq);
  convert_weights<<<2114, 256, 0, stream>>>(W1, W2, Wl, Wr, aw, W1t, W2t, Wlv, Wrv, awh);

  // MLP (bf16 MFMA) + temporal attention
  nt_mfma<1><<<dim3(1, 640), 256, 0, stream>>>(seqbf, W1t, b1, h1bf, 128, 128);
  nt_mfma<2><<<dim3(8, 640), 256, 0, stream>>>(h1bf, W2t, b2, gfea, 128, 0);
  temporal_attn<<<1, 1024, 0, stream>>>(gfea, attn);

  // KNN: coarse bf16 top-20 per column-half (8 blocks/CU) + merge + rescore
  knn_coarse<<<2048, 256, 0, stream>>>(seqbf, xsq, ckeys);
  knn_merge<<<256, 256, 0, stream>>>(ckeys, cand20);
  knn_rescore<<<16384, 256, 0, stream>>>(seq, xsq, cand20, nbr);

  // GAT projections (split-bf16 MFMA -> half)
  nt_mfma<3><<<dim3(4, 128), 256, 0, stream>>>(ylay, Wlv, nullptr, xlh, 384, 512);
  nt_mfma<3><<<dim3(4, 512), 256, 0, stream>>>(xlay, Wrv, nullptr, xrh, 384, 512);

  // GAT gather/softmax/aggregate (XCD-swizzled)
  gat6<<<16384, 256, 0, stream>>>(xlh, xrh, nbr, awh, attn, wgt4);

  finalize2<<<4096, 256, 0, stream>>>(seq + (size_t)4 * 16384 * 128, wgt4, out);
}

// Round 9
// 754.986 us; speedup vs baseline: 2.2047x; 2.2047x over previous
//
#include <hip/hip_runtime.h>
#include <hip/hip_bf16.h>
#include <hip/hip_fp16.h>

// T=5, B=4, M=4096, N=16384, C=128, G=1024, H=4, K=16. fp32 in/out.

typedef __bf16 v8bf __attribute__((ext_vector_type(8)));
typedef float  v4f  __attribute__((ext_vector_type(4)));

__device__ __forceinline__ float lrelu(float x) { return fmaxf(x, 0.2f * x); }

__device__ __forceinline__ unsigned short f2bf(float x) {
  __hip_bfloat16 h = __float2bfloat16(x);
  return __builtin_bit_cast(unsigned short, h);
}
__device__ __forceinline__ float bf2f(unsigned short u) {
  unsigned int t = ((unsigned int)u) << 16;
  return __builtin_bit_cast(float, t);
}

// order-preserving float<->uint key (sign-flip trick)
__device__ __forceinline__ unsigned fkey(float v) {
  unsigned b = __builtin_bit_cast(unsigned, v);
  return b ^ (((unsigned)((int)b >> 31)) | 0x80000000u);
}
__device__ __forceinline__ float finv(unsigned k) {
  unsigned m = (unsigned)((int)k >> 31);           // all-1s iff encoded-positive
  unsigned b = k ^ ((~m) | 0x80000000u);
  return __builtin_bit_cast(float, b);
}

#define GLOAD_LDS16(gp, lp)                                                   \
  __builtin_amdgcn_global_load_lds(                                           \
      (const __attribute__((address_space(1))) void*)(gp),                    \
      (__attribute__((address_space(3))) void*)(lp), 16, 0, 0)

// raw barrier (no vmcnt drain) + IR-level memory fence
#define RBAR() do { __builtin_amdgcn_s_barrier(); asm volatile("" ::: "memory"); } while (0)
// intra-wave LDS drain (no barrier): orders LDS atomics/writes vs later reads
#define LWAIT() do { asm volatile("s_waitcnt lgkmcnt(0)" ::: "memory");        \
                     __builtin_amdgcn_sched_barrier(0); } while (0)

// ---------------------------------------------------------------------------
// Unified NT bf16 MFMA GEMM (MLP + projections) — unchanged.
// ---------------------------------------------------------------------------
template<int EP>
__global__ __launch_bounds__(256, 2)
void nt_mfma(const unsigned short* __restrict__ A, const unsigned short* __restrict__ B,
             const float* __restrict__ aux, void* __restrict__ outv, int K, int ldc)
{
  __shared__ __align__(16) unsigned short smem[3 * 8192];  // 3 x (A 4096 + B 4096)
  const int tid = threadIdx.x;
  const int l = tid & 63;
  const int w = tid >> 6;
  const int wm = w & 1, wn = w >> 1;
  const int m0 = blockIdx.y << 7, n0 = blockIdx.x << 7;
  const int fr = l & 15, quad = l >> 4;
  const int kt = K >> 5;
  const int xq4 = quad ^ ((fr >> 1) & 3);           // read-side swizzle slot

  const int r0 = tid >> 2;
  const int sw = (tid & 3) ^ ((tid >> 3) & 3);      // source-side swizzle slot
  const unsigned short* Aa = A + (size_t)(m0 + r0) * K + sw * 8;
  const unsigned short* Ab = Aa + (size_t)64 * K;
  const unsigned short* Ba = B + (size_t)(n0 + r0) * K + sw * 8;
  const unsigned short* Bb = Ba + (size_t)64 * K;

  auto stage = [&](int bi, int ks) {
    unsigned short* As = smem + bi * 8192;
    unsigned short* Bs = As + 4096;
    GLOAD_LDS16(Aa + ks * 32, As + tid * 8);
    GLOAD_LDS16(Ab + ks * 32, As + (tid + 256) * 8);
    GLOAD_LDS16(Ba + ks * 32, Bs + tid * 8);
    GLOAD_LDS16(Bb + ks * 32, Bs + (tid + 256) * 8);
  };

  v4f acc[4][4];
#pragma unroll
  for (int i = 0; i < 4; ++i)
#pragma unroll
    for (int j = 0; j < 4; ++j) acc[i][j] = (v4f){0.f, 0.f, 0.f, 0.f};

  stage(0, 0);
  if (kt > 1) stage(1, 1);
  int cur = 0, pend = (kt > 1) ? 2 : 1, sn = 2;

  for (int ks = 0; ks < kt; ++ks) {
    if (pend == 2) asm volatile("s_waitcnt vmcnt(4)" ::: "memory");
    else           asm volatile("s_waitcnt vmcnt(0)" ::: "memory");
    RBAR();
    int nb = cur + 2; if (nb >= 3) nb -= 3;
    if (sn < kt) { stage(nb, sn); ++sn; } else { --pend; }
    const unsigned short* As = smem + cur * 8192;
    const unsigned short* Bs = As + 4096;
    v8bf af[4], bfr[4];
#pragma unroll
    for (int i = 0; i < 4; ++i)
      af[i] = *(const v8bf*)(As + (wm * 64 + i * 16 + fr) * 32 + xq4 * 8);
#pragma unroll
    for (int j = 0; j < 4; ++j)
      bfr[j] = *(const v8bf*)(Bs + (wn * 64 + j * 16 + fr) * 32 + xq4 * 8);
#pragma unroll
    for (int i = 0; i < 4; ++i)
#pragma unroll
      for (int j = 0; j < 4; ++j)
        acc[i][j] = __builtin_amdgcn_mfma_f32_16x16x32_bf16(af[i], bfr[j], acc[i][j], 0, 0, 0);
    __builtin_amdgcn_sched_barrier(0);
    if (++cur == 3) cur = 0;
  }

  if (EP == 1) {
    unsigned short* O = (unsigned short*)outv;
#pragma unroll
    for (int j = 0; j < 4; ++j) {
      int col = n0 + wn * 64 + j * 16 + fr;
      float bias = aux[col];
#pragma unroll
      for (int i = 0; i < 4; ++i) {
        int row = m0 + wm * 64 + i * 16 + quad * 4;
#pragma unroll
        for (int r = 0; r < 4; ++r)
          O[(size_t)(row + r) * ldc + col] = f2bf(lrelu(acc[i][j][r] + bias));
      }
    }
  } else if (EP == 2) {
    __syncthreads();
    float* red = (float*)smem;
#pragma unroll
    for (int j = 0; j < 4; ++j) {
      int lcol = wn * 64 + j * 16 + fr;
      float bias = aux[n0 + lcol];
      float s = 0.f;
#pragma unroll
      for (int i = 0; i < 4; ++i)
#pragma unroll
        for (int r = 0; r < 4; ++r) s += lrelu(acc[i][j][r] + bias);
      s += __shfl_xor(s, 16);
      s += __shfl_xor(s, 32);
      if (quad == 0) red[w * 128 + lcol] = s;
    }
    __syncthreads();
    if (tid < 128) {
      float s = (tid < 64) ? red[0 * 128 + tid] + red[1 * 128 + tid]
                           : red[2 * 128 + tid] + red[3 * 128 + tid];
      atomicAdd((float*)outv + ((m0 >> 12) << 10) + n0 + tid, s * (1.0f / 4096.0f));
    }
  } else {  // EP == 3: half store
    __half* O = (__half*)outv;
#pragma unroll
    for (int j = 0; j < 4; ++j) {
      int col = n0 + wn * 64 + j * 16 + fr;
#pragma unroll
      for (int i = 0; i < 4; ++i) {
        int row = m0 + wm * 64 + i * 16 + quad * 4;
#pragma unroll
        for (int r = 0; r < 4; ++r)
          O[(size_t)(row + r) * ldc + col] = __float2half(acc[i][j][r]);
      }
    }
  }
}

// ---------------------------------------------------------------------------
// knn_coarse v10 = r7's PROVEN geometry (grid 1024, (256,4), 64 rows x 4096
// cols, 16 KB B half-tiles, A-from-global, register packed-key top-20 —
// measured 340 us, VGPR 64, no spill) + r8's VALU cuts kept (row-max gate,
// zero-push fast exit). The r8 column-split/(256,8) is REVERTED: it forced a
// 64-VGPR budget on a ~90-VGPR kernel -> full top-list spill, 4.9 GB scratch
// traffic (4th spill incident this session; 4 blocks/CU is this kernel's
// register-feasible occupancy).
// ---------------------------------------------------------------------------
#define TOPN 20
#define FB   10   // push-buffer capacity per row per pass
#define PSTR 11   // push row stride (odd)

__global__ __launch_bounds__(256, 4)
void knn_coarse(const unsigned short* __restrict__ seqbf,
                const float* __restrict__ xsq, int* __restrict__ candOut)
{
  __shared__ __align__(16) unsigned short bsm[8192];  // 16 KB: B half-tile (2 k-chunks)
  __shared__ unsigned pushK[64 * PSTR];
  __shared__ int      cntW[64];

  const int tid = threadIdx.x;
  const int l = tid & 63;
  const int w = tid >> 6;
  const int blk = blockIdx.x;
  const int pair = ((blk & 7) << 1) | ((blk >> 3) & 1);  // XCD-aligned (f,b)
  const int rb = blk >> 4;                               // 0..63
  const int f = pair >> 2, b = pair & 3;
  const int m0 = rb << 6;                                // 64-row block
  const int fr = l & 15, quad = l >> 4;
  const int xq4 = quad ^ ((fr >> 1) & 3);

  const unsigned short* ybase = seqbf + ((size_t)65536 + b * 4096) * 128;
  const unsigned short* xbase = seqbf + ((size_t)(f * 16384 + b * 4096)) * 128;
  const float* xq = xsq + f * 16384 + b * 4096;

  const int r0 = tid >> 2;
  const int sw = (tid & 3) ^ ((tid >> 3) & 3);

  // A fragments straight from global: warp w owns rows [w*16, w*16+16)
  v8bf afr[4];
#pragma unroll
  for (int ksp = 0; ksp < 4; ++ksp)
    afr[ksp] = *(const v8bf*)(ybase + (size_t)(m0 + w * 16 + fr) * 128 + ksp * 32 + quad * 8);

  // register top-list (packed keys, descending); valid on owner lanes l<16
  unsigned tk[TOPN];
#pragma unroll
  for (int k = 0; k < TOPN; ++k) tk[k] = 0u;
  float tauReg = -3.0e38f;
  if (l < 16) cntW[w * 16 + l] = 0;
  float tc[4];
#pragma unroll
  for (int r = 0; r < 4; ++r) tc[r] = -3.0e38f;
  LWAIT();

  for (int ct = 0; ct < 32; ++ct) {
    const int n0 = ct << 7;
    const unsigned short* Bt = xbase + (size_t)(n0 + r0) * 128 + sw * 8;

    // ---- half 0: k-chunks 0,1 ----
    RBAR();  // fence vs all warps' prev-tile half-1 ds_reads
    GLOAD_LDS16(Bt, bsm + tid * 8);
    GLOAD_LDS16(Bt + 64 * 128, bsm + (tid + 256) * 8);
    GLOAD_LDS16(Bt + 32, bsm + 4096 + tid * 8);
    GLOAD_LDS16(Bt + 64 * 128 + 32, bsm + 4096 + (tid + 256) * 8);
    float xsv[8];
#pragma unroll
    for (int j = 0; j < 8; ++j) xsv[j] = xq[n0 + j * 16 + fr];
    asm volatile("s_waitcnt vmcnt(0)" ::: "memory");
    RBAR();

    v4f acc[8];
#pragma unroll
    for (int j = 0; j < 8; ++j) acc[j] = (v4f){0.f, 0.f, 0.f, 0.f};

#pragma unroll
    for (int ksp = 0; ksp < 2; ++ksp) {
      v8bf bfr[8];
#pragma unroll
      for (int j = 0; j < 8; ++j)
        bfr[j] = *(const v8bf*)(bsm + ksp * 4096 + (j * 16 + fr) * 32 + xq4 * 8);
#pragma unroll
      for (int j = 0; j < 8; ++j)
        acc[j] = __builtin_amdgcn_mfma_f32_16x16x32_bf16(afr[ksp], bfr[j], acc[j], 0, 0, 0);
    }
    LWAIT();
    RBAR();

    // ---- half 1: k-chunks 2,3 ----
    GLOAD_LDS16(Bt + 2 * 32, bsm + tid * 8);
    GLOAD_LDS16(Bt + 64 * 128 + 2 * 32, bsm + (tid + 256) * 8);
    GLOAD_LDS16(Bt + 3 * 32, bsm + 4096 + tid * 8);
    GLOAD_LDS16(Bt + 64 * 128 + 3 * 32, bsm + 4096 + (tid + 256) * 8);
    asm volatile("s_waitcnt vmcnt(0)" ::: "memory");
    RBAR();

#pragma unroll
    for (int ksp = 0; ksp < 2; ++ksp) {
      v8bf bfr[8];
#pragma unroll
      for (int j = 0; j < 8; ++j)
        bfr[j] = *(const v8bf*)(bsm + ksp * 4096 + (j * 16 + fr) * 32 + xq4 * 8);
#pragma unroll
      for (int j = 0; j < 8; ++j)
        acc[j] = __builtin_amdgcn_mfma_f32_16x16x32_bf16(afr[2 + ksp], bfr[j], acc[j], 0, 0, 0);
    }

    // fold v = 2*acc - xs in place
#pragma unroll
    for (int j = 0; j < 8; ++j)
#pragma unroll
      for (int r = 0; r < 4; ++r)
        acc[j][r] = 2.f * acc[j][r] - xsv[j];

    if (ct == 0) {
      // tau seed: per row, min over 16 fr-lanes of lane-2nd-max (valid lower
      // bound: >=32 values >= tau0 per row -> fills TOPN=20)
#pragma unroll
      for (int r = 0; r < 4; ++r) {
        float t1 = fmaxf(acc[0][r], acc[1][r]);
        float t2 = fminf(acc[0][r], acc[1][r]);
#pragma unroll
        for (int j = 2; j < 8; ++j) {
          float v = acc[j][r];
          float hi = fmaxf(t1, v);
          t2 = fmaxf(t2, fminf(t1, v));
          t1 = hi;
        }
#pragma unroll
        for (int off = 1; off <= 8; off <<= 1)
          t2 = fminf(t2, __shfl_xor(t2, off));
        tc[r] = t2;
        float tq = __shfl(t2, (l >> 2) << 4);   // value from target row's quad
        if (l < 16 && (l & 3) == r) tauReg = tq;
      }
    }

    // ---- warp-private exact top-20: row-max gate + push + reg-merge ----
    unsigned int pushed = 0u;
    for (;;) {
      bool didPush = false;
      // gate: per r, max over j then one compare (>= matches scan predicate)
      int hit = 0;
#pragma unroll
      for (int r = 0; r < 4; ++r) {
        float m = acc[0][r];
#pragma unroll
        for (int j = 1; j < 8; ++j) m = fmaxf(m, acc[j][r]);
        if (m >= tc[r]) hit |= 1 << r;
      }
      if (__any(hit != 0)) {
#pragma unroll
        for (int r = 0; r < 4; ++r) {
          if (__any(hit & (1 << r))) {
            const float tau = tc[r];
            int mca = 0;
#pragma unroll
            for (int j = 0; j < 8; ++j) {
              const int bit = j * 4 + r;
              if (acc[j][r] >= tau && !((pushed >> bit) & 1u)) mca |= (1 << j);
            }
            if (__any(mca != 0)) {
              const int lrow = w * 16 + quad * 4 + r;
#pragma unroll
              for (int j = 0; j < 8; ++j)
                if ((mca >> j) & 1) {
                  int pos = atomicAdd(&cntW[lrow], 1);
                  if (pos < FB) {
                    pushK[lrow * PSTR + pos] =
                        (fkey(acc[j][r]) & 0xFFFFF000u) | (unsigned)(n0 + j * 16 + fr);
                    pushed |= (1u << (j * 4 + r));
                    didPush = true;
                  }
                }
            }
          }
        }
      }
      if (!__any(didPush)) break;   // nothing pushed anywhere -> done, skip merge
      LWAIT();
      bool ov = false;
      if (l < 16) {
        const int grow = w * 16 + l;
        int c = cntW[grow];
        int cc = c < FB ? c : FB;
        for (int q = 0; q < cc; ++q) {
          unsigned k = pushK[grow * PSTR + q];
          if (k > tk[TOPN - 1]) {
            // static-unrolled descending sorted insert (registers only)
#pragma unroll
            for (int i = TOPN - 1; i >= 1; --i)
              tk[i] = (k > tk[i - 1]) ? tk[i - 1] : (k > tk[i] ? k : tk[i]);
            tk[0] = (k > tk[0]) ? k : tk[0];
          }
        }
        if (tk[TOPN - 1] != 0u)
          tauReg = fmaxf(tauReg, finv(tk[TOPN - 1] & 0xFFFFF000u));
        ov = c > FB;
        cntW[grow] = 0;
      }
      LWAIT();
#pragma unroll
      for (int r = 0; r < 4; ++r)
        tc[r] = __shfl(tauReg, quad * 4 + r);   // owner lane of row quad*4+r
      if (!__any(ov)) break;
    }
  }

  if (l < 16) {
    const int grow = w * 16 + l;
    int* outp = candOut + ((size_t)(f * 16384 + b * 4096 + m0 + grow)) * TOPN;
#pragma unroll
    for (int k = 0; k < TOPN; ++k) outp[k] = (int)(tk[k] & 0xFFFu);
  }
}

// ---------------------------------------------------------------------------
// knn_rescore v4 (unchanged): exact fp32 rescoring of 20 candidates -> top-16.
// ---------------------------------------------------------------------------
__global__ __launch_bounds__(256)
void knn_rescore(const float* __restrict__ seq, const float* __restrict__ xsq,
                 const int* __restrict__ cand, int* __restrict__ nbrOut)
{
  __shared__ float sc[4][20];
  const int tid = threadIdx.x;
  const int l = tid & 63;
  const int wq = tid >> 6;                    // query within block
  const int blk = blockIdx.x;
  const int pair = ((blk & 7) << 1) | ((blk >> 3) & 1);
  const int qb = blk >> 4;                    // 0..1023
  const int f = pair >> 2, b = pair & 3;
  const int qloc = qb * 4 + wq;               // 0..4095
  const int gq = pair * 4096 + qloc;          // = f*16384 + b*4096 + qloc

  const int c8 = l & 7;                       // candidate slot in round
  const int h  = l >> 3;                      // chunk 0..7
  const float* yrow = seq + ((size_t)65536 + b * 4096 + qloc) * 128 + h * 16;
  float4 y0 = *(const float4*)(yrow);
  float4 y1 = *(const float4*)(yrow + 4);
  float4 y2 = *(const float4*)(yrow + 8);
  float4 y3 = *(const float4*)(yrow + 12);
  const float* xslice = seq + (size_t)(f * 16384 + (b << 12)) * 128;
  const float* xsqs = xsq + f * 16384 + (b << 12);
  const int* cq = cand + (size_t)gq * 20;

#pragma unroll
  for (int rd = 0; rd < 3; ++rd) {
    int cr = rd * 8 + c8;
    int crc = cr < 20 ? cr : 0;
    int cj = cq[crc];
    const float* xr = xslice + (size_t)cj * 128 + h * 16;
    float4 x0 = *(const float4*)(xr);
    float4 x1 = *(const float4*)(xr + 4);
    float4 x2 = *(const float4*)(xr + 8);
    float4 x3 = *(const float4*)(xr + 12);
    float p = y0.x * x0.x + y0.y * x0.y + y0.z * x0.z + y0.w * x0.w
            + y1.x * x1.x + y1.y * x1.y + y1.z * x1.z + y1.w * x1.w
            + y2.x * x2.x + y2.y * x2.y + y2.z * x2.z + y2.w * x2.w
            + y3.x * x3.x + y3.y * x3.y + y3.z * x3.z + y3.w * x3.w;
    p += __shfl_xor(p, 8);
    p += __shfl_xor(p, 16);
    p += __shfl_xor(p, 32);
    if (h == 0 && cr < 20) sc[wq][cr] = 2.f * p - xsqs[cj];
  }
  LWAIT();   // sc written/read by the same wave only
  if (l < 20) {
    float myv = sc[wq][l];
    int rank = 0;
#pragma unroll
    for (int j = 0; j < 20; ++j) {
      float vj = sc[wq][j];
      rank += (vj > myv || (vj == myv && j < l)) ? 1 : 0;
    }
    if (rank < 16)
      nbrOut[(size_t)gq * 16 + rank] = (b << 12) + cq[l];
  }
}

// ---------------------------------------------------------------------------
// convert_inputs v2: seqbf (hi-only bf16) + xsq only. ylay/xlay are GONE —
// the projections now read seqbf directly (plain bf16), saving their 96 MB
// construction traffic and the split-bf16 GEMM's 3x FLOPs.
// ---------------------------------------------------------------------------
__global__ __launch_bounds__(256)
void convert_inputs(const float* __restrict__ seq, unsigned short* __restrict__ seqbf,
                    float* __restrict__ xsq)
{
  const int tid = threadIdx.x;
  const int row = blockIdx.x * 8 + (tid >> 5);
  const int c4 = tid & 31;
  float4 v = *(const float4*)(seq + (size_t)row * 128 + c4 * 4);
  ushort4 hi;
  hi.x = f2bf(v.x); hi.y = f2bf(v.y); hi.z = f2bf(v.z); hi.w = f2bf(v.w);
  *(ushort4*)(seqbf + (size_t)row * 128 + c4 * 4) = hi;
  if (row < 65536) {
    float ss = v.x * v.x + v.y * v.y + v.z * v.z + v.w * v.w;
#pragma unroll
    for (int off = 16; off; off >>= 1) ss += __shfl_xor(ss, off);
    if (c4 == 0) xsq[row] = ss;
  }
}

// ---------------------------------------------------------------------------
// convert_weights v2: W1t/W2t as before; Wlv/Wrv are now plain bf16 512x128
// NT matrices (hi-only); awh unchanged. Total 279,040 threads.
// ---------------------------------------------------------------------------
__global__ __launch_bounds__(256)
void convert_weights(const float* __restrict__ W1, const float* __restrict__ W2,
                     const float* __restrict__ Wl, const float* __restrict__ Wr,
                     const float* __restrict__ aw,
                     unsigned short* __restrict__ W1t, unsigned short* __restrict__ W2t,
                     unsigned short* __restrict__ Wlv, unsigned short* __restrict__ Wrv,
                     __half* __restrict__ awh)
{
  int idx = blockIdx.x * 256 + threadIdx.x;
  if (idx < 16384) {
    int n = idx >> 7, k = idx & 127;
    W1t[idx] = f2bf(W1[k * 128 + n]);
  } else if (idx < 147456) {
    int i = idx - 16384; int n = i >> 7, k = i & 127;
    W2t[i] = f2bf(W2[k * 1024 + n]);
  } else if (idx < 212992) {
    int i = idx - 147456; int n = i >> 7, k = i & 127;
    Wlv[i] = f2bf(Wl[k * 512 + n]);
  } else if (idx < 278528) {
    int i = idx - 212992; int n = i >> 7, k = i & 127;
    Wrv[i] = f2bf(Wr[k * 512 + n]);
  } else if (idx < 279040) {
    int i = idx - 278528;
    awh[i] = __float2half(aw[i]);
  }
}

// ---------------------------------------------------------------------------
// Temporal attention weights (unchanged)
// ---------------------------------------------------------------------------
__global__ __launch_bounds__(1024)
void temporal_attn(const float* __restrict__ gfea, float* __restrict__ attnw)
{
  const int tid = threadIdx.x;
  const int w = tid >> 6, l = tid & 63;
  const int b = w >> 2, i = w & 3;
  const float* q  = gfea + (16 + b) * 1024;
  const float* kv = gfea + (i * 4 + b) * 1024;
  float p = 0.f;
  for (int g = l; g < 1024; g += 64) p += q[g] * kv[g];
#pragma unroll
  for (int off = 32; off; off >>= 1) p += __shfl_xor(p, off);
  __shared__ float sc[16];
  if (l == 0) sc[w] = p * 0.03125f;
  __syncthreads();
  if (tid < 4) {
    float v0 = sc[tid * 4 + 0], v1 = sc[tid * 4 + 1];
    float v2 = sc[tid * 4 + 2], v3 = sc[tid * 4 + 3];
    float mm = fmaxf(fmaxf(v0, v1), fmaxf(v2, v3));
    v0 = __expf(v0 - mm); v1 = __expf(v1 - mm);
    v2 = __expf(v2 - mm); v3 = __expf(v3 - mm);
    float inv = 1.f / (v0 + v1 + v2 + v3);
    attnw[tid * 4 + 0] = v0 * inv;
    attnw[tid * 4 + 1] = v1 * inv;
    attnw[tid * 4 + 2] = v2 * inv;
    attnw[tid * 4 + 3] = v3 * inv;
  }
}

// ---------------------------------------------------------------------------
// gat6 (chunked single-fetch) + XCD-aware swizzle (unchanged)
// ---------------------------------------------------------------------------
__global__ __launch_bounds__(256)
void gat6(const __half* __restrict__ xlh, const __half* __restrict__ xrh,
          const int* __restrict__ nbr, const __half* __restrict__ awh,
          const float* __restrict__ attnw, float* __restrict__ wgt4)
{
  const int tid = threadIdx.x;
  const int l = tid & 63;
  const int blk = blockIdx.x;
  const int r8 = blk & 7;
  const int b = r8 >> 1;                      // XCD pair -> batch
  const int g = ((blk >> 3) << 1) | (r8 & 1); // [0, 4096)
  const int f = g >> 10;
  const int n4 = g & 1023;
  const int qid = f * 16384 + b * 4096 + n4 * 4 + (tid >> 6);
  const int h = l >> 4, cp = l & 15;
  const float fw = attnw[b * 4 + f] * 0.25f;

  const int jl = nbr[qid * 16 + (l & 15)];
  const __half* xbase = xlh + h * 128 + cp * 8;

  const __half2* xrp = (const __half2*)(xrh + (size_t)qid * 512 + h * 128 + cp * 8);
  float2 xr0 = __half22float2(xrp[0]), xr1 = __half22float2(xrp[1]);
  float2 xr2 = __half22float2(xrp[2]), xr3 = __half22float2(xrp[3]);
  const __half2* awp = (const __half2*)(awh + h * 128 + cp * 8);
  float2 aw0 = __half22float2(awp[0]), aw1 = __half22float2(awp[1]);
  float2 aw2 = __half22float2(awp[2]), aw3 = __half22float2(awp[3]);

  float m = -3.0e38f, s = 0.f;
  float o[8];
#pragma unroll
  for (int c = 0; c < 8; ++c) o[c] = 0.f;

  for (int ch = 0; ch < 2; ++ch) {
    float4 xv[8];
#pragma unroll
    for (int k = 0; k < 8; ++k) {
      int j = __shfl(jl, ch * 8 + k);
      xv[k] = *(const float4*)(xbase + (size_t)j * 512);
    }
    float e[8];
#pragma unroll
    for (int k = 0; k < 8; ++k) {
      const __half2* hp = (const __half2*)&xv[k];
      float2 x0 = __half22float2(hp[0]), x1 = __half22float2(hp[1]);
      float2 x2 = __half22float2(hp[2]), x3 = __half22float2(hp[3]);
      float p = 0.f;
      p += lrelu(x0.x + xr0.x) * aw0.x + lrelu(x0.y + xr0.y) * aw0.y;
      p += lrelu(x1.x + xr1.x) * aw1.x + lrelu(x1.y + xr1.y) * aw1.y;
      p += lrelu(x2.x + xr2.x) * aw2.x + lrelu(x2.y + xr2.y) * aw2.y;
      p += lrelu(x3.x + xr3.x) * aw3.x + lrelu(x3.y + xr3.y) * aw3.y;
      p += __shfl_xor(p, 1);
      p += __shfl_xor(p, 2);
      p += __shfl_xor(p, 4);
      p += __shfl_xor(p, 8);
      e[k] = p;
    }
    float mc = e[0];
#pragma unroll
    for (int k = 1; k < 8; ++k) mc = fmaxf(mc, e[k]);
    float mn = fmaxf(m, mc);
    float cr = __expf(m - mn);
    s *= cr;
#pragma unroll
    for (int c = 0; c < 8; ++c) o[c] *= cr;
#pragma unroll
    for (int k = 0; k < 8; ++k) {
      float a = __expf(e[k] - mn);
      s += a;
      const __half2* hp = (const __half2*)&xv[k];
      float2 f0 = __half22float2(hp[0]);
      float2 f1 = __half22float2(hp[1]);
      float2 f2 = __half22float2(hp[2]);
      float2 f3 = __half22float2(hp[3]);
      o[0] += a * f0.x; o[1] += a * f0.y;
      o[2] += a * f1.x; o[3] += a * f1.y;
      o[4] += a * f2.x; o[5] += a * f2.y;
      o[6] += a * f3.x; o[7] += a * f3.y;
    }
    m = mn;
  }

  const float sc = fw / s;
#pragma unroll
  for (int c = 0; c < 8; ++c) {
    float t = o[c] * sc;
    t += __shfl_xor(t, 16);
    t += __shfl_xor(t, 32);
    o[c] = t;
  }
  if (l < 16) {
    float* wp = wgt4 + (size_t)qid * 128 + l * 8;
    *(float4*)(wp)     = make_float4(o[0], o[1], o[2], o[3]);
    *(float4*)(wp + 4) = make_float4(o[4], o[5], o[6], o[7]);
  }
}

// ---------------------------------------------------------------------------
// finalize (unchanged)
// ---------------------------------------------------------------------------
__global__ __launch_bounds__(256)
void finalize2(const float* __restrict__ last, const float* __restrict__ wgt4,
               float* __restrict__ out)
{
  int idx = blockIdx.x * 256 + threadIdx.x;
  int n = idx >> 6, q = idx & 63;
  float4 v;
  if (q < 32) {
    v = *(const float4*)(last + (size_t)n * 128 + 4 * q);
  } else {
    int c = (q - 32) * 4;
    v = make_float4(0.f, 0.f, 0.f, 0.f);
#pragma unroll
    for (int f = 0; f < 4; ++f) {
      float4 t = *(const float4*)(wgt4 + ((size_t)f * 16384 + n) * 128 + c);
      v.x += t.x; v.y += t.y; v.z += t.z; v.w += t.w;
    }
  }
  *(float4*)(out + (size_t)n * 256 + 4 * q) = v;
}

extern "C" void kernel_launch(void* const* d_in, const int* in_sizes, int n_in,
                              void* d_out, int out_size, void* d_ws, size_t ws_size,
                              hipStream_t stream)
{
  (void)in_sizes; (void)n_in; (void)out_size; (void)ws_size;
  const float* seq = (const float*)d_in[0];
  const float* W1  = (const float*)d_in[1];
  const float* b1  = (const float*)d_in[2];
  const float* W2  = (const float*)d_in[3];
  const float* b2  = (const float*)d_in[4];
  const float* Wl  = (const float*)d_in[5];
  const float* Wr  = (const float*)d_in[6];
  const float* aw  = (const float*)d_in[7];
  float* out = (float*)d_out;

  // workspace layout (float offsets)
  float* ws = (float*)d_ws;
  __half* xrh          = (__half*)ws;                          // 65536x512 half (32 MB region)
  unsigned short* seqbf = (unsigned short*)(ws + 16777216);    // 10,485,760 us
  unsigned short* h1bf  = (unsigned short*)(ws + 22020096);    // 10,485,760 us
  int* cand20           = (int*)(ws + 22020096);               // alias after mlp2: 65536x20 int
  __half* xlh           = (__half*)(ws + 22020096);            // alias after rescore: 16384x512 half
  float* wgt4           = ws + 30408704;                       // 8,388,608 f
  float* gfea           = ws + 42991616;                       // 20,480
  float* attn           = gfea + 20480;                        // 16
  float* xsq            = attn + 16;                           // 65,536
  int*   nbr            = (int*)(xsq + 65536);                 // 1,048,576 ints
  unsigned short* W1t   = (unsigned short*)(nbr + 1048576);    // 16,384 us
  unsigned short* W2t   = W1t + 16384;                         // 131,072 us
  unsigned short* Wlv   = W2t + 131072;                        // 65,536 us (bf16 512x128)
  unsigned short* Wrv   = Wlv + 65536;                         // 65,536 us
  __half* awh           = (__half*)(Wrv + 65536);              // 512 halves

  (void)hipMemsetAsync(gfea, 0, 20480 * sizeof(float), stream);

  // conversions
  convert_inputs<<<10240, 256, 0, stream>>>(seq, seqbf, xsq);
  convert_weights<<<1090, 256, 0, stream>>>(W1, W2, Wl, Wr, aw, W1t, W2t, Wlv, Wrv, awh);

  // MLP (bf16 MFMA) + temporal attention
  nt_mfma<1><<<dim3(1, 640), 256, 0, stream>>>(seqbf, W1t, b1, h1bf, 128, 128);
  nt_mfma<2><<<dim3(8, 640), 256, 0, stream>>>(h1bf, W2t, b2, gfea, 128, 0);
  temporal_attn<<<1, 1024, 0, stream>>>(gfea, attn);

  // KNN: coarse bf16 top-20 (register packed-key lists) + exact fp32 rescore
  knn_coarse<<<1024, 256, 0, stream>>>(seqbf, xsq, cand20);
  knn_rescore<<<16384, 256, 0, stream>>>(seq, xsq, cand20, nbr);

  // GAT projections: plain bf16 K=128 straight from seqbf
  nt_mfma<3><<<dim3(4, 128), 256, 0, stream>>>(seqbf + (size_t)65536 * 128, Wlv, nullptr, xlh, 128, 512);
  nt_mfma<3><<<dim3(4, 512), 256, 0, stream>>>(seqbf, Wrv, nullptr, xrh, 128, 512);

  // GAT gather/softmax/aggregate (XCD-swizzled)
  gat6<<<16384, 256, 0, stream>>>(xlh, xrh, nbr, awh, attn, wgt4);

  finalize2<<<4096, 256, 0, stream>>>(seq + (size_t)4 * 16384 * 128, wgt4, out);
}

// Round 10
// 749.983 us; speedup vs baseline: 2.2194x; 1.0067x over previous
//
#include <hip/hip_runtime.h>
#include <hip/hip_bf16.h>
#include <hip/hip_fp16.h>

// T=5, B=4, M=4096, N=16384, C=128, G=1024, H=4, K=16. fp32 in/out.

typedef __bf16 v8bf __attribute__((ext_vector_type(8)));
typedef float  v4f  __attribute__((ext_vector_type(4)));

__device__ __forceinline__ float lrelu(float x) { return fmaxf(x, 0.2f * x); }

__device__ __forceinline__ unsigned short f2bf(float x) {
  __hip_bfloat16 h = __float2bfloat16(x);
  return __builtin_bit_cast(unsigned short, h);
}
__device__ __forceinline__ float bf2f(unsigned short u) {
  unsigned int t = ((unsigned int)u) << 16;
  return __builtin_bit_cast(float, t);
}

// order-preserving float<->uint key (sign-flip trick)
__device__ __forceinline__ unsigned fkey(float v) {
  unsigned b = __builtin_bit_cast(unsigned, v);
  return b ^ (((unsigned)((int)b >> 31)) | 0x80000000u);
}
__device__ __forceinline__ float finv(unsigned k) {
  unsigned m = (unsigned)((int)k >> 31);           // all-1s iff encoded-positive
  unsigned b = k ^ ((~m) | 0x80000000u);
  return __builtin_bit_cast(float, b);
}

#define GLOAD_LDS16(gp, lp)                                                   \
  __builtin_amdgcn_global_load_lds(                                           \
      (const __attribute__((address_space(1))) void*)(gp),                    \
      (__attribute__((address_space(3))) void*)(lp), 16, 0, 0)

// raw barrier (no vmcnt drain) + IR-level memory fence
#define RBAR() do { __builtin_amdgcn_s_barrier(); asm volatile("" ::: "memory"); } while (0)
// intra-wave LDS drain (no barrier): orders LDS atomics/writes vs later reads
#define LWAIT() do { asm volatile("s_waitcnt lgkmcnt(0)" ::: "memory");        \
                     __builtin_amdgcn_sched_barrier(0); } while (0)

// ---------------------------------------------------------------------------
// Unified NT bf16 MFMA GEMM (MLP + projections) — unchanged.
// ---------------------------------------------------------------------------
template<int EP>
__global__ __launch_bounds__(256, 2)
void nt_mfma(const unsigned short* __restrict__ A, const unsigned short* __restrict__ B,
             const float* __restrict__ aux, void* __restrict__ outv, int K, int ldc)
{
  __shared__ __align__(16) unsigned short smem[3 * 8192];  // 3 x (A 4096 + B 4096)
  const int tid = threadIdx.x;
  const int l = tid & 63;
  const int w = tid >> 6;
  const int wm = w & 1, wn = w >> 1;
  const int m0 = blockIdx.y << 7, n0 = blockIdx.x << 7;
  const int fr = l & 15, quad = l >> 4;
  const int kt = K >> 5;
  const int xq4 = quad ^ ((fr >> 1) & 3);           // read-side swizzle slot

  const int r0 = tid >> 2;
  const int sw = (tid & 3) ^ ((tid >> 3) & 3);      // source-side swizzle slot
  const unsigned short* Aa = A + (size_t)(m0 + r0) * K + sw * 8;
  const unsigned short* Ab = Aa + (size_t)64 * K;
  const unsigned short* Ba = B + (size_t)(n0 + r0) * K + sw * 8;
  const unsigned short* Bb = Ba + (size_t)64 * K;

  auto stage = [&](int bi, int ks) {
    unsigned short* As = smem + bi * 8192;
    unsigned short* Bs = As + 4096;
    GLOAD_LDS16(Aa + ks * 32, As + tid * 8);
    GLOAD_LDS16(Ab + ks * 32, As + (tid + 256) * 8);
    GLOAD_LDS16(Ba + ks * 32, Bs + tid * 8);
    GLOAD_LDS16(Bb + ks * 32, Bs + (tid + 256) * 8);
  };

  v4f acc[4][4];
#pragma unroll
  for (int i = 0; i < 4; ++i)
#pragma unroll
    for (int j = 0; j < 4; ++j) acc[i][j] = (v4f){0.f, 0.f, 0.f, 0.f};

  stage(0, 0);
  if (kt > 1) stage(1, 1);
  int cur = 0, pend = (kt > 1) ? 2 : 1, sn = 2;

  for (int ks = 0; ks < kt; ++ks) {
    if (pend == 2) asm volatile("s_waitcnt vmcnt(4)" ::: "memory");
    else           asm volatile("s_waitcnt vmcnt(0)" ::: "memory");
    RBAR();
    int nb = cur + 2; if (nb >= 3) nb -= 3;
    if (sn < kt) { stage(nb, sn); ++sn; } else { --pend; }
    const unsigned short* As = smem + cur * 8192;
    const unsigned short* Bs = As + 4096;
    v8bf af[4], bfr[4];
#pragma unroll
    for (int i = 0; i < 4; ++i)
      af[i] = *(const v8bf*)(As + (wm * 64 + i * 16 + fr) * 32 + xq4 * 8);
#pragma unroll
    for (int j = 0; j < 4; ++j)
      bfr[j] = *(const v8bf*)(Bs + (wn * 64 + j * 16 + fr) * 32 + xq4 * 8);
#pragma unroll
    for (int i = 0; i < 4; ++i)
#pragma unroll
      for (int j = 0; j < 4; ++j)
        acc[i][j] = __builtin_amdgcn_mfma_f32_16x16x32_bf16(af[i], bfr[j], acc[i][j], 0, 0, 0);
    __builtin_amdgcn_sched_barrier(0);
    if (++cur == 3) cur = 0;
  }

  if (EP == 1) {
    unsigned short* O = (unsigned short*)outv;
#pragma unroll
    for (int j = 0; j < 4; ++j) {
      int col = n0 + wn * 64 + j * 16 + fr;
      float bias = aux[col];
#pragma unroll
      for (int i = 0; i < 4; ++i) {
        int row = m0 + wm * 64 + i * 16 + quad * 4;
#pragma unroll
        for (int r = 0; r < 4; ++r)
          O[(size_t)(row + r) * ldc + col] = f2bf(lrelu(acc[i][j][r] + bias));
      }
    }
  } else if (EP == 2) {
    __syncthreads();
    float* red = (float*)smem;
#pragma unroll
    for (int j = 0; j < 4; ++j) {
      int lcol = wn * 64 + j * 16 + fr;
      float bias = aux[n0 + lcol];
      float s = 0.f;
#pragma unroll
      for (int i = 0; i < 4; ++i)
#pragma unroll
        for (int r = 0; r < 4; ++r) s += lrelu(acc[i][j][r] + bias);
      s += __shfl_xor(s, 16);
      s += __shfl_xor(s, 32);
      if (quad == 0) red[w * 128 + lcol] = s;
    }
    __syncthreads();
    if (tid < 128) {
      float s = (tid < 64) ? red[0 * 128 + tid] + red[1 * 128 + tid]
                           : red[2 * 128 + tid] + red[3 * 128 + tid];
      atomicAdd((float*)outv + ((m0 >> 12) << 10) + n0 + tid, s * (1.0f / 4096.0f));
    }
  } else {  // EP == 3: half store
    __half* O = (__half*)outv;
#pragma unroll
    for (int j = 0; j < 4; ++j) {
      int col = n0 + wn * 64 + j * 16 + fr;
#pragma unroll
      for (int i = 0; i < 4; ++i) {
        int row = m0 + wm * 64 + i * 16 + quad * 4;
#pragma unroll
        for (int r = 0; r < 4; ++r)
          O[(size_t)(row + r) * ldc + col] = __float2half(acc[i][j][r]);
      }
    }
  }
}

// ---------------------------------------------------------------------------
// knn_coarse v11 = v10 with the register clamp REMOVED:
// r9's counters showed VGPR_Count=64 + ~12 MB unexplained FETCH/WRITE = the
// AMDGPU allocator squeezed a ~90-VGPR-live kernel into 64 regs (chasing
// 8-waves/EU occupancy the 1024-block grid can never realize; grid caps at
// 4 blocks/CU) and quietly spilled part of tk[]/afr[]. amdgpu_waves_per_eu(4,4)
// pins the occupancy assumption at exactly 4 waves/EU -> allocator may use up
// to 128 VGPR -> top-list stays fully in registers. No numerics change.
// ---------------------------------------------------------------------------
#define TOPN 20
#define FB   10   // push-buffer capacity per row per pass
#define PSTR 11   // push row stride (odd)

__global__ __launch_bounds__(256)
__attribute__((amdgpu_waves_per_eu(4, 4)))
void knn_coarse(const unsigned short* __restrict__ seqbf,
                const float* __restrict__ xsq, int* __restrict__ candOut)
{
  __shared__ __align__(16) unsigned short bsm[8192];  // 16 KB: B half-tile (2 k-chunks)
  __shared__ unsigned pushK[64 * PSTR];
  __shared__ int      cntW[64];

  const int tid = threadIdx.x;
  const int l = tid & 63;
  const int w = tid >> 6;
  const int blk = blockIdx.x;
  const int pair = ((blk & 7) << 1) | ((blk >> 3) & 1);  // XCD-aligned (f,b)
  const int rb = blk >> 4;                               // 0..63
  const int f = pair >> 2, b = pair & 3;
  const int m0 = rb << 6;                                // 64-row block
  const int fr = l & 15, quad = l >> 4;
  const int xq4 = quad ^ ((fr >> 1) & 3);

  const unsigned short* ybase = seqbf + ((size_t)65536 + b * 4096) * 128;
  const unsigned short* xbase = seqbf + ((size_t)(f * 16384 + b * 4096)) * 128;
  const float* xq = xsq + f * 16384 + b * 4096;

  const int r0 = tid >> 2;
  const int sw = (tid & 3) ^ ((tid >> 3) & 3);

  // A fragments straight from global: warp w owns rows [w*16, w*16+16)
  v8bf afr[4];
#pragma unroll
  for (int ksp = 0; ksp < 4; ++ksp)
    afr[ksp] = *(const v8bf*)(ybase + (size_t)(m0 + w * 16 + fr) * 128 + ksp * 32 + quad * 8);

  // register top-list (packed keys, descending); valid on owner lanes l<16
  unsigned tk[TOPN];
#pragma unroll
  for (int k = 0; k < TOPN; ++k) tk[k] = 0u;
  float tauReg = -3.0e38f;
  if (l < 16) cntW[w * 16 + l] = 0;
  float tc[4];
#pragma unroll
  for (int r = 0; r < 4; ++r) tc[r] = -3.0e38f;
  LWAIT();

  for (int ct = 0; ct < 32; ++ct) {
    const int n0 = ct << 7;
    const unsigned short* Bt = xbase + (size_t)(n0 + r0) * 128 + sw * 8;

    // ---- half 0: k-chunks 0,1 ----
    RBAR();  // fence vs all warps' prev-tile half-1 ds_reads
    GLOAD_LDS16(Bt, bsm + tid * 8);
    GLOAD_LDS16(Bt + 64 * 128, bsm + (tid + 256) * 8);
    GLOAD_LDS16(Bt + 32, bsm + 4096 + tid * 8);
    GLOAD_LDS16(Bt + 64 * 128 + 32, bsm + 4096 + (tid + 256) * 8);
    float xsv[8];
#pragma unroll
    for (int j = 0; j < 8; ++j) xsv[j] = xq[n0 + j * 16 + fr];
    asm volatile("s_waitcnt vmcnt(0)" ::: "memory");
    RBAR();

    v4f acc[8];
#pragma unroll
    for (int j = 0; j < 8; ++j) acc[j] = (v4f){0.f, 0.f, 0.f, 0.f};

#pragma unroll
    for (int ksp = 0; ksp < 2; ++ksp) {
      v8bf bfr[8];
#pragma unroll
      for (int j = 0; j < 8; ++j)
        bfr[j] = *(const v8bf*)(bsm + ksp * 4096 + (j * 16 + fr) * 32 + xq4 * 8);
#pragma unroll
      for (int j = 0; j < 8; ++j)
        acc[j] = __builtin_amdgcn_mfma_f32_16x16x32_bf16(afr[ksp], bfr[j], acc[j], 0, 0, 0);
    }
    LWAIT();
    RBAR();

    // ---- half 1: k-chunks 2,3 ----
    GLOAD_LDS16(Bt + 2 * 32, bsm + tid * 8);
    GLOAD_LDS16(Bt + 64 * 128 + 2 * 32, bsm + (tid + 256) * 8);
    GLOAD_LDS16(Bt + 3 * 32, bsm + 4096 + tid * 8);
    GLOAD_LDS16(Bt + 64 * 128 + 3 * 32, bsm + 4096 + (tid + 256) * 8);
    asm volatile("s_waitcnt vmcnt(0)" ::: "memory");
    RBAR();

#pragma unroll
    for (int ksp = 0; ksp < 2; ++ksp) {
      v8bf bfr[8];
#pragma unroll
      for (int j = 0; j < 8; ++j)
        bfr[j] = *(const v8bf*)(bsm + ksp * 4096 + (j * 16 + fr) * 32 + xq4 * 8);
#pragma unroll
      for (int j = 0; j < 8; ++j)
        acc[j] = __builtin_amdgcn_mfma_f32_16x16x32_bf16(afr[2 + ksp], bfr[j], acc[j], 0, 0, 0);
    }

    // fold v = 2*acc - xs in place
#pragma unroll
    for (int j = 0; j < 8; ++j)
#pragma unroll
      for (int r = 0; r < 4; ++r)
        acc[j][r] = 2.f * acc[j][r] - xsv[j];

    if (ct == 0) {
      // tau seed: per row, min over 16 fr-lanes of lane-2nd-max (valid lower
      // bound: >=32 values >= tau0 per row -> fills TOPN=20)
#pragma unroll
      for (int r = 0; r < 4; ++r) {
        float t1 = fmaxf(acc[0][r], acc[1][r]);
        float t2 = fminf(acc[0][r], acc[1][r]);
#pragma unroll
        for (int j = 2; j < 8; ++j) {
          float v = acc[j][r];
          float hi = fmaxf(t1, v);
          t2 = fmaxf(t2, fminf(t1, v));
          t1 = hi;
        }
#pragma unroll
        for (int off = 1; off <= 8; off <<= 1)
          t2 = fminf(t2, __shfl_xor(t2, off));
        tc[r] = t2;
        float tq = __shfl(t2, (l >> 2) << 4);   // value from target row's quad
        if (l < 16 && (l & 3) == r) tauReg = tq;
      }
    }

    // ---- warp-private exact top-20: row-max gate + push + reg-merge ----
    unsigned int pushed = 0u;
    for (;;) {
      bool didPush = false;
      // gate: per r, max over j then one compare (>= matches scan predicate)
      int hit = 0;
#pragma unroll
      for (int r = 0; r < 4; ++r) {
        float m = acc[0][r];
#pragma unroll
        for (int j = 1; j < 8; ++j) m = fmaxf(m, acc[j][r]);
        if (m >= tc[r]) hit |= 1 << r;
      }
      if (__any(hit != 0)) {
#pragma unroll
        for (int r = 0; r < 4; ++r) {
          if (__any(hit & (1 << r))) {
            const float tau = tc[r];
            int mca = 0;
#pragma unroll
            for (int j = 0; j < 8; ++j) {
              const int bit = j * 4 + r;
              if (acc[j][r] >= tau && !((pushed >> bit) & 1u)) mca |= (1 << j);
            }
            if (__any(mca != 0)) {
              const int lrow = w * 16 + quad * 4 + r;
#pragma unroll
              for (int j = 0; j < 8; ++j)
                if ((mca >> j) & 1) {
                  int pos = atomicAdd(&cntW[lrow], 1);
                  if (pos < FB) {
                    pushK[lrow * PSTR + pos] =
                        (fkey(acc[j][r]) & 0xFFFFF000u) | (unsigned)(n0 + j * 16 + fr);
                    pushed |= (1u << (j * 4 + r));
                    didPush = true;
                  }
                }
            }
          }
        }
      }
      if (!__any(didPush)) break;   // nothing pushed anywhere -> done, skip merge
      LWAIT();
      bool ov = false;
      if (l < 16) {
        const int grow = w * 16 + l;
        int c = cntW[grow];
        int cc = c < FB ? c : FB;
        for (int q = 0; q < cc; ++q) {
          unsigned k = pushK[grow * PSTR + q];
          if (k > tk[TOPN - 1]) {
            // static-unrolled descending sorted insert (registers only)
#pragma unroll
            for (int i = TOPN - 1; i >= 1; --i)
              tk[i] = (k > tk[i - 1]) ? tk[i - 1] : (k > tk[i] ? k : tk[i]);
            tk[0] = (k > tk[0]) ? k : tk[0];
          }
        }
        if (tk[TOPN - 1] != 0u)
          tauReg = fmaxf(tauReg, finv(tk[TOPN - 1] & 0xFFFFF000u));
        ov = c > FB;
        cntW[grow] = 0;
      }
      LWAIT();
#pragma unroll
      for (int r = 0; r < 4; ++r)
        tc[r] = __shfl(tauReg, quad * 4 + r);   // owner lane of row quad*4+r
      if (!__any(ov)) break;
    }
  }

  if (l < 16) {
    const int grow = w * 16 + l;
    int* outp = candOut + ((size_t)(f * 16384 + b * 4096 + m0 + grow)) * TOPN;
#pragma unroll
    for (int k = 0; k < TOPN; ++k) outp[k] = (int)(tk[k] & 0xFFFu);
  }
}

// ---------------------------------------------------------------------------
// knn_rescore v4 (unchanged): exact fp32 rescoring of 20 candidates -> top-16.
// ---------------------------------------------------------------------------
__global__ __launch_bounds__(256)
void knn_rescore(const float* __restrict__ seq, const float* __restrict__ xsq,
                 const int* __restrict__ cand, int* __restrict__ nbrOut)
{
  __shared__ float sc[4][20];
  const int tid = threadIdx.x;
  const int l = tid & 63;
  const int wq = tid >> 6;                    // query within block
  const int blk = blockIdx.x;
  const int pair = ((blk & 7) << 1) | ((blk >> 3) & 1);
  const int qb = blk >> 4;                    // 0..1023
  const int f = pair >> 2, b = pair & 3;
  const int qloc = qb * 4 + wq;               // 0..4095
  const int gq = pair * 4096 + qloc;          // = f*16384 + b*4096 + qloc

  const int c8 = l & 7;                       // candidate slot in round
  const int h  = l >> 3;                      // chunk 0..7
  const float* yrow = seq + ((size_t)65536 + b * 4096 + qloc) * 128 + h * 16;
  float4 y0 = *(const float4*)(yrow);
  float4 y1 = *(const float4*)(yrow + 4);
  float4 y2 = *(const float4*)(yrow + 8);
  float4 y3 = *(const float4*)(yrow + 12);
  const float* xslice = seq + (size_t)(f * 16384 + (b << 12)) * 128;
  const float* xsqs = xsq + f * 16384 + (b << 12);
  const int* cq = cand + (size_t)gq * 20;

#pragma unroll
  for (int rd = 0; rd < 3; ++rd) {
    int cr = rd * 8 + c8;
    int crc = cr < 20 ? cr : 0;
    int cj = cq[crc];
    const float* xr = xslice + (size_t)cj * 128 + h * 16;
    float4 x0 = *(const float4*)(xr);
    float4 x1 = *(const float4*)(xr + 4);
    float4 x2 = *(const float4*)(xr + 8);
    float4 x3 = *(const float4*)(xr + 12);
    float p = y0.x * x0.x + y0.y * x0.y + y0.z * x0.z + y0.w * x0.w
            + y1.x * x1.x + y1.y * x1.y + y1.z * x1.z + y1.w * x1.w
            + y2.x * x2.x + y2.y * x2.y + y2.z * x2.z + y2.w * x2.w
            + y3.x * x3.x + y3.y * x3.y + y3.z * x3.z + y3.w * x3.w;
    p += __shfl_xor(p, 8);
    p += __shfl_xor(p, 16);
    p += __shfl_xor(p, 32);
    if (h == 0 && cr < 20) sc[wq][cr] = 2.f * p - xsqs[cj];
  }
  LWAIT();   // sc written/read by the same wave only
  if (l < 20) {
    float myv = sc[wq][l];
    int rank = 0;
#pragma unroll
    for (int j = 0; j < 20; ++j) {
      float vj = sc[wq][j];
      rank += (vj > myv || (vj == myv && j < l)) ? 1 : 0;
    }
    if (rank < 16)
      nbrOut[(size_t)gq * 16 + rank] = (b << 12) + cq[l];
  }
}

// ---------------------------------------------------------------------------
// convert_inputs v2 (unchanged from r9)
// ---------------------------------------------------------------------------
__global__ __launch_bounds__(256)
void convert_inputs(const float* __restrict__ seq, unsigned short* __restrict__ seqbf,
                    float* __restrict__ xsq)
{
  const int tid = threadIdx.x;
  const int row = blockIdx.x * 8 + (tid >> 5);
  const int c4 = tid & 31;
  float4 v = *(const float4*)(seq + (size_t)row * 128 + c4 * 4);
  ushort4 hi;
  hi.x = f2bf(v.x); hi.y = f2bf(v.y); hi.z = f2bf(v.z); hi.w = f2bf(v.w);
  *(ushort4*)(seqbf + (size_t)row * 128 + c4 * 4) = hi;
  if (row < 65536) {
    float ss = v.x * v.x + v.y * v.y + v.z * v.z + v.w * v.w;
#pragma unroll
    for (int off = 16; off; off >>= 1) ss += __shfl_xor(ss, off);
    if (c4 == 0) xsq[row] = ss;
  }
}

// ---------------------------------------------------------------------------
// convert_weights v2 (unchanged from r9)
// ---------------------------------------------------------------------------
__global__ __launch_bounds__(256)
void convert_weights(const float* __restrict__ W1, const float* __restrict__ W2,
                     const float* __restrict__ Wl, const float* __restrict__ Wr,
                     const float* __restrict__ aw,
                     unsigned short* __restrict__ W1t, unsigned short* __restrict__ W2t,
                     unsigned short* __restrict__ Wlv, unsigned short* __restrict__ Wrv,
                     __half* __restrict__ awh)
{
  int idx = blockIdx.x * 256 + threadIdx.x;
  if (idx < 16384) {
    int n = idx >> 7, k = idx & 127;
    W1t[idx] = f2bf(W1[k * 128 + n]);
  } else if (idx < 147456) {
    int i = idx - 16384; int n = i >> 7, k = i & 127;
    W2t[i] = f2bf(W2[k * 1024 + n]);
  } else if (idx < 212992) {
    int i = idx - 147456; int n = i >> 7, k = i & 127;
    Wlv[i] = f2bf(Wl[k * 512 + n]);
  } else if (idx < 278528) {
    int i = idx - 212992; int n = i >> 7, k = i & 127;
    Wrv[i] = f2bf(Wr[k * 512 + n]);
  } else if (idx < 279040) {
    int i = idx - 278528;
    awh[i] = __float2half(aw[i]);
  }
}

// ---------------------------------------------------------------------------
// Temporal attention weights (unchanged)
// ---------------------------------------------------------------------------
__global__ __launch_bounds__(1024)
void temporal_attn(const float* __restrict__ gfea, float* __restrict__ attnw)
{
  const int tid = threadIdx.x;
  const int w = tid >> 6, l = tid & 63;
  const int b = w >> 2, i = w & 3;
  const float* q  = gfea + (16 + b) * 1024;
  const float* kv = gfea + (i * 4 + b) * 1024;
  float p = 0.f;
  for (int g = l; g < 1024; g += 64) p += q[g] * kv[g];
#pragma unroll
  for (int off = 32; off; off >>= 1) p += __shfl_xor(p, off);
  __shared__ float sc[16];
  if (l == 0) sc[w] = p * 0.03125f;
  __syncthreads();
  if (tid < 4) {
    float v0 = sc[tid * 4 + 0], v1 = sc[tid * 4 + 1];
    float v2 = sc[tid * 4 + 2], v3 = sc[tid * 4 + 3];
    float mm = fmaxf(fmaxf(v0, v1), fmaxf(v2, v3));
    v0 = __expf(v0 - mm); v1 = __expf(v1 - mm);
    v2 = __expf(v2 - mm); v3 = __expf(v3 - mm);
    float inv = 1.f / (v0 + v1 + v2 + v3);
    attnw[tid * 4 + 0] = v0 * inv;
    attnw[tid * 4 + 1] = v1 * inv;
    attnw[tid * 4 + 2] = v2 * inv;
    attnw[tid * 4 + 3] = v3 * inv;
  }
}

// ---------------------------------------------------------------------------
// gat6 (chunked single-fetch) + XCD-aware swizzle (unchanged)
// ---------------------------------------------------------------------------
__global__ __launch_bounds__(256)
void gat6(const __half* __restrict__ xlh, const __half* __restrict__ xrh,
          const int* __restrict__ nbr, const __half* __restrict__ awh,
          const float* __restrict__ attnw, float* __restrict__ wgt4)
{
  const int tid = threadIdx.x;
  const int l = tid & 63;
  const int blk = blockIdx.x;
  const int r8 = blk & 7;
  const int b = r8 >> 1;                      // XCD pair -> batch
  const int g = ((blk >> 3) << 1) | (r8 & 1); // [0, 4096)
  const int f = g >> 10;
  const int n4 = g & 1023;
  const int qid = f * 16384 + b * 4096 + n4 * 4 + (tid >> 6);
  const int h = l >> 4, cp = l & 15;
  const float fw = attnw[b * 4 + f] * 0.25f;

  const int jl = nbr[qid * 16 + (l & 15)];
  const __half* xbase = xlh + h * 128 + cp * 8;

  const __half2* xrp = (const __half2*)(xrh + (size_t)qid * 512 + h * 128 + cp * 8);
  float2 xr0 = __half22float2(xrp[0]), xr1 = __half22float2(xrp[1]);
  float2 xr2 = __half22float2(xrp[2]), xr3 = __half22float2(xrp[3]);
  const __half2* awp = (const __half2*)(awh + h * 128 + cp * 8);
  float2 aw0 = __half22float2(awp[0]), aw1 = __half22float2(awp[1]);
  float2 aw2 = __half22float2(awp[2]), aw3 = __half22float2(awp[3]);

  float m = -3.0e38f, s = 0.f;
  float o[8];
#pragma unroll
  for (int c = 0; c < 8; ++c) o[c] = 0.f;

  for (int ch = 0; ch < 2; ++ch) {
    float4 xv[8];
#pragma unroll
    for (int k = 0; k < 8; ++k) {
      int j = __shfl(jl, ch * 8 + k);
      xv[k] = *(const float4*)(xbase + (size_t)j * 512);
    }
    float e[8];
#pragma unroll
    for (int k = 0; k < 8; ++k) {
      const __half2* hp = (const __half2*)&xv[k];
      float2 x0 = __half22float2(hp[0]), x1 = __half22float2(hp[1]);
      float2 x2 = __half22float2(hp[2]), x3 = __half22float2(hp[3]);
      float p = 0.f;
      p += lrelu(x0.x + xr0.x) * aw0.x + lrelu(x0.y + xr0.y) * aw0.y;
      p += lrelu(x1.x + xr1.x) * aw1.x + lrelu(x1.y + xr1.y) * aw1.y;
      p += lrelu(x2.x + xr2.x) * aw2.x + lrelu(x2.y + xr2.y) * aw2.y;
      p += lrelu(x3.x + xr3.x) * aw3.x + lrelu(x3.y + xr3.y) * aw3.y;
      p += __shfl_xor(p, 1);
      p += __shfl_xor(p, 2);
      p += __shfl_xor(p, 4);
      p += __shfl_xor(p, 8);
      e[k] = p;
    }
    float mc = e[0];
#pragma unroll
    for (int k = 1; k < 8; ++k) mc = fmaxf(mc, e[k]);
    float mn = fmaxf(m, mc);
    float cr = __expf(m - mn);
    s *= cr;
#pragma unroll
    for (int c = 0; c < 8; ++c) o[c] *= cr;
#pragma unroll
    for (int k = 0; k < 8; ++k) {
      float a = __expf(e[k] - mn);
      s += a;
      const __half2* hp = (const __half2*)&xv[k];
      float2 f0 = __half22float2(hp[0]);
      float2 f1 = __half22float2(hp[1]);
      float2 f2 = __half22float2(hp[2]);
      float2 f3 = __half22float2(hp[3]);
      o[0] += a * f0.x; o[1] += a * f0.y;
      o[2] += a * f1.x; o[3] += a * f1.y;
      o[4] += a * f2.x; o[5] += a * f2.y;
      o[6] += a * f3.x; o[7] += a * f3.y;
    }
    m = mn;
  }

  const float sc = fw / s;
#pragma unroll
  for (int c = 0; c < 8; ++c) {
    float t = o[c] * sc;
    t += __shfl_xor(t, 16);
    t += __shfl_xor(t, 32);
    o[c] = t;
  }
  if (l < 16) {
    float* wp = wgt4 + (size_t)qid * 128 + l * 8;
    *(float4*)(wp)     = make_float4(o[0], o[1], o[2], o[3]);
    *(float4*)(wp + 4) = make_float4(o[4], o[5], o[6], o[7]);
  }
}

// ---------------------------------------------------------------------------
// finalize (unchanged)
// ---------------------------------------------------------------------------
__global__ __launch_bounds__(256)
void finalize2(const float* __restrict__ last, const float* __restrict__ wgt4,
               float* __restrict__ out)
{
  int idx = blockIdx.x * 256 + threadIdx.x;
  int n = idx >> 6, q = idx & 63;
  float4 v;
  if (q < 32) {
    v = *(const float4*)(last + (size_t)n * 128 + 4 * q);
  } else {
    int c = (q - 32) * 4;
    v = make_float4(0.f, 0.f, 0.f, 0.f);
#pragma unroll
    for (int f = 0; f < 4; ++f) {
      float4 t = *(const float4*)(wgt4 + ((size_t)f * 16384 + n) * 128 + c);
      v.x += t.x; v.y += t.y; v.z += t.z; v.w += t.w;
    }
  }
  *(float4*)(out + (size_t)n * 256 + 4 * q) = v;
}

extern "C" void kernel_launch(void* const* d_in, const int* in_sizes, int n_in,
                              void* d_out, int out_size, void* d_ws, size_t ws_size,
                              hipStream_t stream)
{
  (void)in_sizes; (void)n_in; (void)out_size; (void)ws_size;
  const float* seq = (const float*)d_in[0];
  const float* W1  = (const float*)d_in[1];
  const float* b1  = (const float*)d_in[2];
  const float* W2  = (const float*)d_in[3];
  const float* b2  = (const float*)d_in[4];
  const float* Wl  = (const float*)d_in[5];
  const float* Wr  = (const float*)d_in[6];
  const float* aw  = (const float*)d_in[7];
  float* out = (float*)d_out;

  // workspace layout (float offsets)
  float* ws = (float*)d_ws;
  __half* xrh          = (__half*)ws;                          // 65536x512 half (32 MB region)
  unsigned short* seqbf = (unsigned short*)(ws + 16777216);    // 10,485,760 us
  unsigned short* h1bf  = (unsigned short*)(ws + 22020096);    // 10,485,760 us
  int* cand20           = (int*)(ws + 22020096);               // alias after mlp2: 65536x20 int
  __half* xlh           = (__half*)(ws + 22020096);            // alias after rescore: 16384x512 half
  float* wgt4           = ws + 30408704;                       // 8,388,608 f
  float* gfea           = ws + 42991616;                       // 20,480
  float* attn           = gfea + 20480;                        // 16
  float* xsq            = attn + 16;                           // 65,536
  int*   nbr            = (int*)(xsq + 65536);                 // 1,048,576 ints
  unsigned short* W1t   = (unsigned short*)(nbr + 1048576);    // 16,384 us
  unsigned short* W2t   = W1t + 16384;                         // 131,072 us
  unsigned short* Wlv   = W2t + 131072;                        // 65,536 us (bf16 512x128)
  unsigned short* Wrv   = Wlv + 65536;                         // 65,536 us
  __half* awh           = (__half*)(Wrv + 65536);              // 512 halves

  (void)hipMemsetAsync(gfea, 0, 20480 * sizeof(float), stream);

  // conversions
  convert_inputs<<<10240, 256, 0, stream>>>(seq, seqbf, xsq);
  convert_weights<<<1090, 256, 0, stream>>>(W1, W2, Wl, Wr, aw, W1t, W2t, Wlv, Wrv, awh);

  // MLP (bf16 MFMA) + temporal attention
  nt_mfma<1><<<dim3(1, 640), 256, 0, stream>>>(seqbf, W1t, b1, h1bf, 128, 128);
  nt_mfma<2><<<dim3(8, 640), 256, 0, stream>>>(h1bf, W2t, b2, gfea, 128, 0);
  temporal_attn<<<1, 1024, 0, stream>>>(gfea, attn);

  // KNN: coarse bf16 top-20 (register packed-key lists) + exact fp32 rescore
  knn_coarse<<<1024, 256, 0, stream>>>(seqbf, xsq, cand20);
  knn_rescore<<<16384, 256, 0, stream>>>(seq, xsq, cand20, nbr);

  // GAT projections: plain bf16 K=128 straight from seqbf
  nt_mfma<3><<<dim3(4, 128), 256, 0, stream>>>(seqbf + (size_t)65536 * 128, Wlv, nullptr, xlh, 128, 512);
  nt_mfma<3><<<dim3(4, 512), 256, 0, stream>>>(seqbf, Wrv, nullptr, xrh, 128, 512);

  // GAT gather/softmax/aggregate (XCD-swizzled)
  gat6<<<16384, 256, 0, stream>>>(xlh, xrh, nbr, awh, attn, wgt4);

  finalize2<<<4096, 256, 0, stream>>>(seq + (size_t)4 * 16384 * 128, wgt4, out);
}